// Round 4
// baseline (356.834 us; speedup 1.0000x reference)
//
#include <hip/hip_runtime.h>
#include <hip/hip_bf16.h>
#include <math.h>

#define B_SZ 2
#define L_SZ 1024
#define DM 1024
#define DI 2048
#define NS 16
#define DTR 64
#define NCHUNK 16
#define CLEN 64
#define XDLD 128  // padded x_dbl leading dim
#define KSPLIT 8

typedef unsigned short ushortT;
typedef __attribute__((ext_vector_type(8))) short short8;
typedef __attribute__((ext_vector_type(4))) float floatx4;

__device__ __forceinline__ ushortT f2bf(float f) {
  unsigned u = __float_as_uint(f);
  unsigned r = (u + 0x7fff + ((u >> 16) & 1)) >> 16;
  return (ushortT)r;
}

__device__ __forceinline__ float bf2f(ushortT v) {
  return __uint_as_float((unsigned)v << 16);
}

__device__ __forceinline__ float fexp2(float x) {
  float r;
  asm("v_exp_f32 %0, %1" : "=v"(r) : "v"(x));
  return r;
}

__device__ __forceinline__ void gl2lds16(const void* g, void* l) {
  __builtin_amdgcn_global_load_lds(
      (const __attribute__((address_space(1))) unsigned int*)g,
      (__attribute__((address_space(3))) unsigned int*)l, 16, 0, 0);
}

// ---------------- fused prep: cvt + 3 transposes + wx_pad ----------------
__device__ __forceinline__ void tr_body(const float* __restrict__ src,
                                        ushortT* __restrict__ dst, int R, int C,
                                        int bx, int by, int tx, int ty,
                                        float (*t)[33]) {
#pragma unroll
  for (int j = 0; j < 4; ++j)
    t[ty + j * 8][tx] = src[(size_t)(by + ty + j * 8) * C + bx + tx];
  __syncthreads();
#pragma unroll
  for (int j = 0; j < 4; ++j)
    dst[(size_t)(bx + ty + j * 8) * R + by + tx] = f2bf(t[tx][ty + j * 8]);
}

// grid ranges: [0,2048) cvt hidden | [2048,6144) Win-T | [6144,7168) Wx pad-T
//              [7168,7296) Wdt-T | [7296,9344) Wout-T
__global__ __launch_bounds__(256) void prep_all(
    const float* __restrict__ hidden, ushortT* __restrict__ hidb,
    const float* __restrict__ Win, ushortT* __restrict__ WinT,
    const float* __restrict__ Wx, ushortT* __restrict__ WxT,
    const float* __restrict__ Wdt, ushortT* __restrict__ WdtT,
    const float* __restrict__ Wout, ushortT* __restrict__ WoutT) {
  __shared__ float t[32][33];
  const int blk = blockIdx.x;
  const int tid = threadIdx.x;
  const int tx = tid & 31, ty = tid >> 5;
  if (blk < 2048) {
    const int i = blk * 256 + tid;
    float4 v = ((const float4*)hidden)[i];
    unsigned lo = (unsigned)f2bf(v.x) | ((unsigned)f2bf(v.y) << 16);
    unsigned hi = (unsigned)f2bf(v.z) | ((unsigned)f2bf(v.w) << 16);
    ((uint2*)hidb)[i] = make_uint2(lo, hi);
  } else if (blk < 6144) {
    const int rel = blk - 2048;  // (128, 32): C=4096, R=1024
    tr_body(Win, WinT, DM, 2 * DI, (rel & 127) * 32, (rel >> 7) * 32, tx, ty, t);
  } else if (blk < 7168) {
    const int rel = blk - 6144;  // (8, 128)
    const int k = (rel & 7) * 256 + tid;
    const int n = rel >> 3;
    WxT[(size_t)n * DI + k] = (n < 96) ? f2bf(Wx[(size_t)k * 96 + n]) : (ushortT)0;
  } else if (blk < 7296) {
    const int rel = blk - 7168;  // (64, 2): C=2048, R=64
    tr_body(Wdt, WdtT, DTR, DI, (rel & 63) * 32, (rel >> 6) * 32, tx, ty, t);
  } else {
    const int rel = blk - 7296;  // (32, 64): C=1024, R=2048
    tr_body(Wout, WoutT, DI, DM, (rel & 31) * 32, (rel >> 5) * 32, tx, ty, t);
  }
}

// ---------------- GEMM1: 128x128 tile, BK=64, 8 waves (512 thr), 512 blocks ----------------
__global__ __launch_bounds__(512) void gemm1_big(
    const ushortT* __restrict__ A, int lda,
    const ushortT* __restrict__ BT, int ldb,
    float* __restrict__ C, int ldc, int K) {
  __shared__ __align__(16) char smem[128 * 128 + 128 * 128];  // A 16KB | B 16KB
  char* As = smem;
  char* Bs = smem + 128 * 128;
  const int tid = threadIdx.x;
  const int lane = tid & 63;
  const int quad = lane >> 4;
  const int l16 = lane & 15;
  const int wid = tid >> 6;
  const int wm = wid & 1;   // 2 m-halves of 64
  const int wn = wid >> 1;  // 4 n-quarters of 32
  const int m0 = blockIdx.y * 128;
  const int n0 = blockIdx.x * 128;

  floatx4 acc[4][2] = {};

  for (int k0 = 0; k0 < K; k0 += 64) {
    for (int i = tid; i < 128 * 8; i += 512) {
      const int r = i >> 3, c = i & 7;
      const int cg = c ^ (r & 7);
      gl2lds16(A + (size_t)(m0 + r) * lda + k0 + cg * 8, As + (i - lane) * 16);
    }
    for (int i = tid; i < 128 * 8; i += 512) {
      const int r = i >> 3, c = i & 7;
      const int cg = c ^ (r & 7);
      gl2lds16(BT + (size_t)(n0 + r) * ldb + k0 + cg * 8, Bs + (i - lane) * 16);
    }
    __syncthreads();

    short8 afr[4][2], bfr[2][2];
#pragma unroll
    for (int i = 0; i < 4; ++i) {
      const int r = wm * 64 + i * 16 + l16;
#pragma unroll
      for (int s = 0; s < 2; ++s)
        afr[i][s] = *(const short8*)(As + r * 128 + (((s * 4 + quad) ^ (r & 7)) * 16));
    }
#pragma unroll
    for (int j = 0; j < 2; ++j) {
      const int r = wn * 32 + j * 16 + l16;
#pragma unroll
      for (int s = 0; s < 2; ++s)
        bfr[j][s] = *(const short8*)(Bs + r * 128 + (((s * 4 + quad) ^ (r & 7)) * 16));
    }
#pragma unroll
    for (int s = 0; s < 2; ++s)
#pragma unroll
      for (int i = 0; i < 4; ++i)
#pragma unroll
        for (int j = 0; j < 2; ++j)
          acc[i][j] = __builtin_amdgcn_mfma_f32_16x16x32_bf16(afr[i][s], bfr[j][s],
                                                              acc[i][j], 0, 0, 0);
    __syncthreads();
  }
#pragma unroll
  for (int i = 0; i < 4; ++i)
#pragma unroll
    for (int j = 0; j < 2; ++j)
#pragma unroll
      for (int r = 0; r < 4; ++r) {
        const int m = m0 + wm * 64 + i * 16 + quad * 4 + r;
        const int n = n0 + wn * 32 + j * 16 + l16;
        C[(size_t)m * ldc + n] = acc[i][j][r];
      }
}

// ---------------- GEMM4: 64x64 tile, BK=64, K=2048, 4 waves, 512 blocks, direct out --------
__global__ __launch_bounds__(256) void gemm_out(
    const ushortT* __restrict__ A, int lda,
    const ushortT* __restrict__ BT, int ldb,
    float* __restrict__ C) {
  __shared__ __align__(16) char smem[64 * 128 + 64 * 128];  // 8KB + 8KB
  char* As = smem;
  char* Bs = smem + 64 * 128;
  const int tid = threadIdx.x;
  const int lane = tid & 63;
  const int quad = lane >> 4;
  const int l16 = lane & 15;
  const int wid = tid >> 6;
  const int wm = wid & 1;   // 2 m-halves of 32
  const int wn = wid >> 1;  // 2 n-halves of 32
  const int m0 = blockIdx.y * 64;
  const int n0 = blockIdx.x * 64;

  floatx4 acc[2][2] = {};

  for (int k0 = 0; k0 < DI; k0 += 64) {
    for (int i = tid; i < 64 * 8; i += 256) {
      const int r = i >> 3, c = i & 7;
      const int cg = c ^ (r & 7);
      gl2lds16(A + (size_t)(m0 + r) * lda + k0 + cg * 8, As + (i - lane) * 16);
    }
    for (int i = tid; i < 64 * 8; i += 256) {
      const int r = i >> 3, c = i & 7;
      const int cg = c ^ (r & 7);
      gl2lds16(BT + (size_t)(n0 + r) * ldb + k0 + cg * 8, Bs + (i - lane) * 16);
    }
    __syncthreads();

    short8 afr[2][2], bfr[2][2];
#pragma unroll
    for (int i = 0; i < 2; ++i) {
      const int m = wm * 32 + i * 16 + l16;
#pragma unroll
      for (int s = 0; s < 2; ++s)
        afr[i][s] = *(const short8*)(As + m * 128 + (((s * 4 + quad) ^ (m & 7)) * 16));
    }
#pragma unroll
    for (int j = 0; j < 2; ++j) {
      const int n = wn * 32 + j * 16 + l16;
#pragma unroll
      for (int s = 0; s < 2; ++s)
        bfr[j][s] = *(const short8*)(Bs + n * 128 + (((s * 4 + quad) ^ (n & 7)) * 16));
    }
#pragma unroll
    for (int s = 0; s < 2; ++s)
#pragma unroll
      for (int i = 0; i < 2; ++i)
#pragma unroll
        for (int j = 0; j < 2; ++j)
          acc[i][j] = __builtin_amdgcn_mfma_f32_16x16x32_bf16(afr[i][s], bfr[j][s],
                                                              acc[i][j], 0, 0, 0);
    __syncthreads();
  }
#pragma unroll
  for (int i = 0; i < 2; ++i)
#pragma unroll
    for (int j = 0; j < 2; ++j)
#pragma unroll
      for (int r = 0; r < 4; ++r) {
        const int m = m0 + wm * 32 + i * 16 + quad * 4 + r;
        const int n = n0 + wn * 32 + j * 16 + l16;
        C[(size_t)m * DM + n] = acc[i][j][r];
      }
}

// ------------- x_dbl partials: xc(bf16) @ Wx (padded N=128), K-split via MFMA -------------
__global__ __launch_bounds__(256) void gemm_xdbl_mfma(
    const ushortT* __restrict__ xcb, const ushortT* __restrict__ WxT,
    float* __restrict__ part) {
  __shared__ __align__(16) char smem[64 * 64 + 128 * 64];
  char* As = smem;             // [64 r][64 B bf16]
  char* Bs = smem + 64 * 64;   // [128 r][64 B bf16]
  const int tid = threadIdx.x;
  const int lane = tid & 63;
  const int quad = lane >> 4;
  const int l16 = lane & 15;
  const int wid = tid >> 6;
  const int wm = wid & 1;
  const int wn = wid >> 1;
  const int m0 = blockIdx.x * 64;
  const int kbase = blockIdx.y * (DI / KSPLIT);

  floatx4 acc[2][4] = {};

  for (int kk = 0; kk < DI / KSPLIT; kk += 32) {
    const int k0 = kbase + kk;
    for (int i = tid; i < 64 * 4; i += 256) {
      const int r = i >> 2, c = i & 3;
      const int cg = c ^ (r & 3);
      gl2lds16(xcb + (size_t)(m0 + r) * DI + k0 + cg * 8, As + (i - lane) * 16);
    }
    for (int i = tid; i < 128 * 4; i += 256) {
      const int r = i >> 2, c = i & 3;
      const int cg = c ^ (r & 3);
      gl2lds16(WxT + (size_t)r * DI + k0 + cg * 8, Bs + (i - lane) * 16);
    }
    __syncthreads();

    short8 afr[2], bfr[4];
#pragma unroll
    for (int i = 0; i < 2; ++i) {
      const int m = wm * 32 + i * 16 + l16;
      afr[i] = *(const short8*)(As + m * 64 + ((quad ^ (m & 3)) * 16));
    }
#pragma unroll
    for (int j = 0; j < 4; ++j) {
      const int n = wn * 64 + j * 16 + l16;
      bfr[j] = *(const short8*)(Bs + n * 64 + ((quad ^ (n & 3)) * 16));
    }
#pragma unroll
    for (int i = 0; i < 2; ++i)
#pragma unroll
      for (int j = 0; j < 4; ++j)
        acc[i][j] = __builtin_amdgcn_mfma_f32_16x16x32_bf16(afr[i], bfr[j],
                                                            acc[i][j], 0, 0, 0);
    __syncthreads();
  }
  float* out = part + (size_t)blockIdx.y * (B_SZ * L_SZ * XDLD);
#pragma unroll
  for (int i = 0; i < 2; ++i)
#pragma unroll
    for (int j = 0; j < 4; ++j)
#pragma unroll
      for (int r = 0; r < 4; ++r) {
        const int m = m0 + wm * 32 + i * 16 + quad * 4 + r;
        const int n = wn * 64 + j * 16 + l16;
        out[(size_t)m * XDLD + n] = acc[i][j][r];
      }
}

// ------------- xdbl = sum of KSPLIT partials; also emit dt cols 0..63 as bf16 -------------
__global__ __launch_bounds__(256) void xdbl_reduce(const float* __restrict__ part,
                                                   float* __restrict__ xdbl,
                                                   ushortT* __restrict__ dtb) {
  const int i = blockIdx.x * 256 + threadIdx.x;  // float4 index, [0, 65536)
  float4 a = ((const float4*)part)[i];
#pragma unroll
  for (int s = 1; s < KSPLIT; ++s) {
    const float4 b = ((const float4*)part)[(size_t)s * (B_SZ * L_SZ * XDLD / 4) + i];
    a.x += b.x; a.y += b.y; a.z += b.z; a.w += b.w;
  }
  ((float4*)xdbl)[i] = a;
  // dt = xdbl[:, 0:64] -> compact bf16 [2048][64] for gemm_delta's A operand
  const int row = i >> 5;           // 32 float4 per 128-col row
  const int c4 = (i & 31) * 4;      // column of this float4
  if (c4 < DTR) {
    const unsigned lo = (unsigned)f2bf(a.x) | ((unsigned)f2bf(a.y) << 16);
    const unsigned hi = (unsigned)f2bf(a.z) | ((unsigned)f2bf(a.w) << 16);
    ((uint2*)dtb)[row * (DTR / 4) + (c4 >> 2)] = make_uint2(lo, hi);
  }
}

// ------------- causal depthwise conv (k=4) + silu -> xc bf16 (8-row tiles) -------------
__global__ __launch_bounds__(256) void conv_silu(
    const float* __restrict__ xz, const float* __restrict__ kern,
    const float* __restrict__ bias, ushortT* __restrict__ xcb) {
  const int d = blockIdx.y * 256 + threadIdx.x;
  const int b = blockIdx.x >> 7;           // 128 8-row chunks per batch
  const int l0 = (blockIdx.x & 127) * 8;
  const int row0 = b * L_SZ + l0;
  const float k0v = kern[0 * DI + d], k1v = kern[1 * DI + d];
  const float k2v = kern[2 * DI + d], k3v = kern[3 * DI + d];
  float xv[11];
#pragma unroll
  for (int i = 0; i < 11; ++i) {
    const int l = l0 - 3 + i;
    xv[i] = (l >= 0) ? xz[((size_t)(b * L_SZ + l)) * 4096 + d] : 0.f;
  }
  const float bs = bias[d];
#pragma unroll
  for (int j = 0; j < 8; ++j) {
    float a = bs;
    a = fmaf(xv[j], k0v, a);
    a = fmaf(xv[j + 1], k1v, a);
    a = fmaf(xv[j + 2], k2v, a);
    a = fmaf(xv[j + 3], k3v, a);
    xcb[(size_t)(row0 + j) * DI + d] = f2bf(a / (1.f + __expf(-a)));
  }
}

// ------------- delta = softplus(dt @ Wdt + dt_bias), pure bf16, single K=64 stage -------------
__global__ __launch_bounds__(256) void gemm_delta_mfma(
    const ushortT* __restrict__ dtb, const ushortT* __restrict__ WdtT,
    const float* __restrict__ dt_bias, float* __restrict__ delta) {
  __shared__ __align__(16) char smem[64 * 128 + 64 * 128];  // A 8KB | B 8KB
  char* As = smem;
  char* Bs = smem + 64 * 128;
  const int tid = threadIdx.x;
  const int lane = tid & 63;
  const int quad = lane >> 4;
  const int l16 = lane & 15;
  const int wid = tid >> 6;
  const int wm = wid & 1;
  const int wn = wid >> 1;
  const int m0 = blockIdx.x * 64;
  const int n0 = blockIdx.y * 64;

  // Stage A (dt bf16 [64][64]) and B (WdtT [64][64]) — full K=64, one shot.
  for (int i = tid; i < 64 * 8; i += 256) {
    const int r = i >> 3, c = i & 7;
    const int cg = c ^ (r & 7);
    gl2lds16(dtb + (size_t)(m0 + r) * DTR + cg * 8, As + (i - lane) * 16);
  }
  for (int i = tid; i < 64 * 8; i += 256) {
    const int r = i >> 3, c = i & 7;
    const int cg = c ^ (r & 7);
    gl2lds16(WdtT + (size_t)(n0 + r) * DTR + cg * 8, Bs + (i - lane) * 16);
  }
  __syncthreads();

  floatx4 acc[2][2] = {};
  short8 afr[2][2], bfr[2][2];
#pragma unroll
  for (int i = 0; i < 2; ++i) {
    const int m = wm * 32 + i * 16 + l16;
#pragma unroll
    for (int s = 0; s < 2; ++s)
      afr[i][s] = *(const short8*)(As + m * 128 + (((s * 4 + quad) ^ (m & 7)) * 16));
  }
#pragma unroll
  for (int j = 0; j < 2; ++j) {
    const int n = wn * 32 + j * 16 + l16;
#pragma unroll
    for (int s = 0; s < 2; ++s)
      bfr[j][s] = *(const short8*)(Bs + n * 128 + (((s * 4 + quad) ^ (n & 7)) * 16));
  }
#pragma unroll
  for (int s = 0; s < 2; ++s)
#pragma unroll
    for (int i = 0; i < 2; ++i)
#pragma unroll
      for (int j = 0; j < 2; ++j)
        acc[i][j] = __builtin_amdgcn_mfma_f32_16x16x32_bf16(afr[i][s], bfr[j][s],
                                                            acc[i][j], 0, 0, 0);

#pragma unroll
  for (int i = 0; i < 2; ++i)
#pragma unroll
    for (int j = 0; j < 2; ++j) {
      const int n = n0 + wn * 32 + j * 16 + l16;
      const float bias = dt_bias[n];
#pragma unroll
      for (int r = 0; r < 4; ++r) {
        const int m = m0 + wm * 32 + i * 16 + quad * 4 + r;
        const float a = acc[i][j][r] + bias;
        // softplus: a>20 guard covers overflow; expf underflow -> log(1)=0 is exact.
        delta[(size_t)m * DI + n] = (a > 20.f) ? a : __logf(1.f + __expf(a));
      }
    }
}

// ------------- fused single-pass selective scan + gate -> y bf16 -------------
// 256 blocks x 128 thr: block = (b, 16 d's); 8 threads/d (nq), 2 states/thread.
// Sequential over all L=1024 steps; B/C double-buffered in LDS per 64-row chunk;
// delta/u/z register-prefetched one 8-step group ahead. Each nq-lane owns one
// output row per 8-group (gate cost amortized /8).
__global__ __launch_bounds__(128) void scan_full(
    const float* __restrict__ delta, const ushortT* __restrict__ xcb,
    const float* __restrict__ xdbl, const float* __restrict__ A_log,
    const float* __restrict__ Dskip, float* __restrict__ xz) {
  __shared__ __align__(16) float BC[2][CLEN][32];  // [buf][row][B:0..16 | C:16..32]
  const int b = blockIdx.x >> 7;
  const int d0 = (blockIdx.x & 127) * 16;
  const int tid = threadIdx.x;
  const int lane = tid & 63;
  const int nq = tid & 7;
  const int d = d0 + (tid >> 3);
  const int rowB = b * L_SZ;

  const float* dp = delta + (size_t)rowB * DI + d;
  const ushortT* up = xcb + (size_t)rowB * DI + d;
  const float* zp = xz + (size_t)rowB * 4096 + DI + d;
  ushortT* yb = (ushortT*)xz;

  // A with log2(e) pre-folded: dA = exp2(delta * Av2)
  float Av2[2];
#pragma unroll
  for (int j = 0; j < 2; ++j)
    Av2[j] = -__expf(A_log[d * 16 + nq * 2 + j]) * 1.44269504f;
  const float Dsk = Dskip[d];

  // stage chunk 0 (rows 0..63): 32 floats (B|C) per row from xdbl cols 64..96
  for (int i = tid; i < 512; i += 128) {
    const int r = i >> 3, q = i & 7;
    gl2lds16(xdbl + (size_t)(rowB + r) * XDLD + 64 + q * 4,
             (char*)&BC[0][0][0] + (size_t)(i - lane) * 16);
  }

  // prefetch group 0 (steps 0..7)
  float dB[8];
  ushortT uB[8];
#pragma unroll
  for (int j = 0; j < 8; ++j) {
    dB[j] = dp[(size_t)j * DI];
    uB[j] = up[(size_t)j * DI];
  }
  float zB = zp[(size_t)nq * 4096];
  float uzB = bf2f(up[(size_t)nq * DI]);

  float x0 = 0.f, x1 = 0.f;
  __syncthreads();  // BC chunk 0 ready

  for (int c = 0; c < NCHUNK; ++c) {
    // issue next chunk's B/C stage into the other buffer (drained by chunk-end barrier)
    if (c + 1 < NCHUNK) {
      const int rb = rowB + (c + 1) * CLEN;
      for (int i = tid; i < 512; i += 128) {
        const int r = i >> 3, q = i & 7;
        gl2lds16(xdbl + (size_t)(rb + r) * XDLD + 64 + q * 4,
                 (char*)&BC[(c + 1) & 1][0][0] + (size_t)(i - lane) * 16);
      }
    }
    const float(*bc)[32] = BC[c & 1];
#pragma unroll 1
    for (int g = 0; g < 8; ++g) {
      const int gl0 = c * CLEN + g * 8;
      const int nr = gl0 + 8;
      // prefetch next 8-step group
      float dN[8] = {};
      ushortT uN[8] = {};
      float zN = 0.f, uzN = 0.f;
      if (nr < L_SZ) {
#pragma unroll
        for (int j = 0; j < 8; ++j) {
          dN[j] = dp[(size_t)(nr + j) * DI];
          uN[j] = up[(size_t)(nr + j) * DI];
        }
        zN = zp[(size_t)(nr + nq) * 4096];
        uzN = bf2f(up[(size_t)(nr + nq) * DI]);
      }
      float yk = 0.f;
#pragma unroll
      for (int j = 0; j < 8; ++j) {
        const int l = g * 8 + j;
        const float2 Bv = *(const float2*)&bc[l][nq * 2];
        const float2 Cv = *(const float2*)&bc[l][16 + nq * 2];
        const float dlt = dB[j];
        const float t = dlt * bf2f(uB[j]);
        const float dA0 = fexp2(dlt * Av2[0]);
        const float dA1 = fexp2(dlt * Av2[1]);
        x0 = fmaf(dA0, x0, t * Bv.x);
        x1 = fmaf(dA1, x1, t * Bv.y);
        float y = x0 * Cv.x;
        y = fmaf(x1, Cv.y, y);
        y += __shfl_xor(y, 1);
        y += __shfl_xor(y, 2);
        y += __shfl_xor(y, 4);
        yk = (nq == j) ? y : yk;  // lane nq keeps step j==nq
      }
      // gate + store this lane's assigned row (gl0 + nq)
      const float sig = zB / (1.f + __expf(-zB));
      yb[(size_t)(rowB + gl0 + nq) * 8192 + d] = f2bf(fmaf(uzB, Dsk, yk) * sig);
#pragma unroll
      for (int j = 0; j < 8; ++j) { dB[j] = dN[j]; uB[j] = uN[j]; }
      zB = zN;
      uzB = uzN;
    }
    __syncthreads();  // compute done + next-chunk stage drained
  }
}

extern "C" void kernel_launch(void* const* d_in, const int* in_sizes, int n_in,
                              void* d_out, int out_size, void* d_ws, size_t ws_size,
                              hipStream_t stream) {
  const float* hidden  = (const float*)d_in[0];
  const float* Win     = (const float*)d_in[1];
  const float* Wx      = (const float*)d_in[2];
  const float* Wdt     = (const float*)d_in[3];
  const float* dt_bias = (const float*)d_in[4];
  const float* Wout    = (const float*)d_in[5];
  const float* dwk     = (const float*)d_in[6];
  const float* dwb     = (const float*)d_in[7];
  const float* A_log   = (const float*)d_in[8];
  const float* Dskip   = (const float*)d_in[9];

  // ws (64 MB): xz 32MB | shared16 (WinT -> xdbl partials -> delta) 16MB
  //             | [48,56M) xcb bf16 | [56,60M) WoutT bf16 | [60,64M) free
  // xz per-row float layout: [0,1024) y-bf16 | [1024,2048) dead | [2048,4096) z
  char* ws = (char*)d_ws;
  float* xz       = (float*)ws;
  float* shared16 = (float*)(ws + (32u << 20));
  ushortT* xcb    = (ushortT*)(ws + (48u << 20));
  ushortT* WoutT  = (ushortT*)(ws + (56u << 20));
  // d_out (8 MB) scratch: hidb [0,4M) (dead after GEMM1); xdbl128 [4M,5M);
  //                       WxT [5M,5.5M); WdtT [5.5M,5.75M); dtb [5.75M,6M)
  // all dead before gemm_out overwrites d_out with the final result.
  char* dob = (char*)d_out;
  ushortT* hidb = (ushortT*)dob;
  float* xdbl   = (float*)(dob + (4u << 20));
  ushortT* WxT  = (ushortT*)(dob + (5u << 20));
  ushortT* WdtT = (ushortT*)(dob + (5u << 20) + (512u << 10));
  ushortT* dtb  = (ushortT*)(dob + (5u << 20) + (768u << 10));

  // 1. fused prep: hidden->bf16, Win^T, Wx pad^T, Wdt^T, Wout^T
  prep_all<<<dim3(9344), 256, 0, stream>>>(hidden, hidb, Win, (ushortT*)shared16,
                                           Wx, WxT, Wdt, WdtT, Wout, WoutT);
  // 2. GEMM1: xz = hidden @ Win  (M=2048, N=4096, K=1024); 128x128, 8 waves, 512 blocks
  gemm1_big<<<dim3(4096 / 128, 2048 / 128), 512, 0, stream>>>(
      hidb, DM, (ushortT*)shared16, DM, xz, 2 * DI, DM);
  // 3. depthwise conv + silu -> xc bf16 (8-row tiles)
  conv_silu<<<dim3(B_SZ * L_SZ / 8, DI / 256), 256, 0, stream>>>(xz, dwk, dwb, xcb);
  // 4. x_dbl partials (K-split 8) -> shared16 [0,8M) (WinT dead), then reduce (+dt bf16)
  gemm_xdbl_mfma<<<dim3(B_SZ * L_SZ / 64, KSPLIT), 256, 0, stream>>>(
      xcb, WxT, shared16);
  xdbl_reduce<<<dim3(B_SZ * L_SZ * XDLD / 1024), 256, 0, stream>>>(shared16, xdbl, dtb);
  // 5. delta = softplus(dt @ Wdt + bias): pure-bf16 MFMA, single K=64 stage, 1024 blocks
  gemm_delta_mfma<<<dim3(B_SZ * L_SZ / 64, DI / 64), 256, 0, stream>>>(
      dtb, WdtT, dt_bias, shared16);
  // 6. single-pass selective scan + gate -> y bf16 into xz cols [0,1024)
  scan_full<<<dim3(256), 128, 0, stream>>>(shared16, xcb, xdbl, A_log, Dskip, xz);
  // 7. GEMM4: out = y @ Wout (M=2048, N=1024, K=2048), direct write to d_out
  gemm_out<<<dim3(DM / 64, 2048 / 64), 256, 0, stream>>>(
      (ushortT*)xz, 4 * DI, WoutT, DI, (float*)d_out);
}

// Round 5
// 226.806 us; speedup vs baseline: 1.5733x; 1.5733x over previous
//
#include <hip/hip_runtime.h>
#include <hip/hip_bf16.h>
#include <math.h>

#define B_SZ 2
#define L_SZ 1024
#define DM 1024
#define DI 2048
#define NS 16
#define DTR 64
#define NCHUNK 16
#define CLEN 64
#define XDLD 128  // padded x_dbl leading dim
#define KSPLIT 8

typedef unsigned short ushortT;
typedef __attribute__((ext_vector_type(8))) short short8;
typedef __attribute__((ext_vector_type(4))) float floatx4;

__device__ __forceinline__ ushortT f2bf(float f) {
  unsigned u = __float_as_uint(f);
  unsigned r = (u + 0x7fff + ((u >> 16) & 1)) >> 16;
  return (ushortT)r;
}

__device__ __forceinline__ float bf2f(ushortT v) {
  return __uint_as_float((unsigned)v << 16);
}

__device__ __forceinline__ float fexp2(float x) {
  float r;
  asm("v_exp_f32 %0, %1" : "=v"(r) : "v"(x));
  return r;
}

__device__ __forceinline__ void gl2lds16(const void* g, void* l) {
  __builtin_amdgcn_global_load_lds(
      (const __attribute__((address_space(1))) unsigned int*)g,
      (__attribute__((address_space(3))) unsigned int*)l, 16, 0, 0);
}

// Scan-state stash lives in the dead strided region of xz: floats [1024,2048)
// of each 4096-float row. i in [0, 2M): aprod at i, sfin at i + 1M.
__device__ __forceinline__ unsigned stash_addr(unsigned i) {
  return (i >> 10) * 4096 + 1024 + (i & 1023);
}

// ---------------- fused prep: cvt + 3 transposes + wx_pad ----------------
__device__ __forceinline__ void tr_body(const float* __restrict__ src,
                                        ushortT* __restrict__ dst, int R, int C,
                                        int bx, int by, int tx, int ty,
                                        float (*t)[33]) {
#pragma unroll
  for (int j = 0; j < 4; ++j)
    t[ty + j * 8][tx] = src[(size_t)(by + ty + j * 8) * C + bx + tx];
  __syncthreads();
#pragma unroll
  for (int j = 0; j < 4; ++j)
    dst[(size_t)(bx + ty + j * 8) * R + by + tx] = f2bf(t[tx][ty + j * 8]);
}

// grid ranges: [0,2048) cvt hidden | [2048,6144) Win-T | [6144,7168) Wx pad-T
//              [7168,7296) Wdt-T | [7296,9344) Wout-T
__global__ __launch_bounds__(256) void prep_all(
    const float* __restrict__ hidden, ushortT* __restrict__ hidb,
    const float* __restrict__ Win, ushortT* __restrict__ WinT,
    const float* __restrict__ Wx, ushortT* __restrict__ WxT,
    const float* __restrict__ Wdt, ushortT* __restrict__ WdtT,
    const float* __restrict__ Wout, ushortT* __restrict__ WoutT) {
  __shared__ float t[32][33];
  const int blk = blockIdx.x;
  const int tid = threadIdx.x;
  const int tx = tid & 31, ty = tid >> 5;
  if (blk < 2048) {
    const int i = blk * 256 + tid;
    float4 v = ((const float4*)hidden)[i];
    unsigned lo = (unsigned)f2bf(v.x) | ((unsigned)f2bf(v.y) << 16);
    unsigned hi = (unsigned)f2bf(v.z) | ((unsigned)f2bf(v.w) << 16);
    ((uint2*)hidb)[i] = make_uint2(lo, hi);
  } else if (blk < 6144) {
    const int rel = blk - 2048;  // (128, 32): C=4096, R=1024
    tr_body(Win, WinT, DM, 2 * DI, (rel & 127) * 32, (rel >> 7) * 32, tx, ty, t);
  } else if (blk < 7168) {
    const int rel = blk - 6144;  // (8, 128)
    const int k = (rel & 7) * 256 + tid;
    const int n = rel >> 3;
    WxT[(size_t)n * DI + k] = (n < 96) ? f2bf(Wx[(size_t)k * 96 + n]) : (ushortT)0;
  } else if (blk < 7296) {
    const int rel = blk - 7168;  // (64, 2): C=2048, R=64
    tr_body(Wdt, WdtT, DTR, DI, (rel & 63) * 32, (rel >> 6) * 32, tx, ty, t);
  } else {
    const int rel = blk - 7296;  // (32, 64): C=1024, R=2048
    tr_body(Wout, WoutT, DI, DM, (rel & 31) * 32, (rel >> 5) * 32, tx, ty, t);
  }
}

// ---------------- GEMM1: 128x128 tile, BK=64, 8 waves (512 thr), 512 blocks ----------------
__global__ __launch_bounds__(512) void gemm1_big(
    const ushortT* __restrict__ A, int lda,
    const ushortT* __restrict__ BT, int ldb,
    float* __restrict__ C, int ldc, int K) {
  __shared__ __align__(16) char smem[128 * 128 + 128 * 128];  // A 16KB | B 16KB
  char* As = smem;
  char* Bs = smem + 128 * 128;
  const int tid = threadIdx.x;
  const int lane = tid & 63;
  const int quad = lane >> 4;
  const int l16 = lane & 15;
  const int wid = tid >> 6;
  const int wm = wid & 1;   // 2 m-halves of 64
  const int wn = wid >> 1;  // 4 n-quarters of 32
  const int m0 = blockIdx.y * 128;
  const int n0 = blockIdx.x * 128;

  floatx4 acc[4][2] = {};

  for (int k0 = 0; k0 < K; k0 += 64) {
    for (int i = tid; i < 128 * 8; i += 512) {
      const int r = i >> 3, c = i & 7;
      const int cg = c ^ (r & 7);
      gl2lds16(A + (size_t)(m0 + r) * lda + k0 + cg * 8, As + (i - lane) * 16);
    }
    for (int i = tid; i < 128 * 8; i += 512) {
      const int r = i >> 3, c = i & 7;
      const int cg = c ^ (r & 7);
      gl2lds16(BT + (size_t)(n0 + r) * ldb + k0 + cg * 8, Bs + (i - lane) * 16);
    }
    __syncthreads();

    short8 afr[4][2], bfr[2][2];
#pragma unroll
    for (int i = 0; i < 4; ++i) {
      const int r = wm * 64 + i * 16 + l16;
#pragma unroll
      for (int s = 0; s < 2; ++s)
        afr[i][s] = *(const short8*)(As + r * 128 + (((s * 4 + quad) ^ (r & 7)) * 16));
    }
#pragma unroll
    for (int j = 0; j < 2; ++j) {
      const int r = wn * 32 + j * 16 + l16;
#pragma unroll
      for (int s = 0; s < 2; ++s)
        bfr[j][s] = *(const short8*)(Bs + r * 128 + (((s * 4 + quad) ^ (r & 7)) * 16));
    }
#pragma unroll
    for (int s = 0; s < 2; ++s)
#pragma unroll
      for (int i = 0; i < 4; ++i)
#pragma unroll
        for (int j = 0; j < 2; ++j)
          acc[i][j] = __builtin_amdgcn_mfma_f32_16x16x32_bf16(afr[i][s], bfr[j][s],
                                                              acc[i][j], 0, 0, 0);
    __syncthreads();
  }
#pragma unroll
  for (int i = 0; i < 4; ++i)
#pragma unroll
    for (int j = 0; j < 2; ++j)
#pragma unroll
      for (int r = 0; r < 4; ++r) {
        const int m = m0 + wm * 64 + i * 16 + quad * 4 + r;
        const int n = n0 + wn * 32 + j * 16 + l16;
        C[(size_t)m * ldc + n] = acc[i][j][r];
      }
}

// ---------------- GEMM4: 64x64 tile, BK=64, K=2048, 4 waves, 512 blocks, direct out --------
__global__ __launch_bounds__(256) void gemm_out(
    const ushortT* __restrict__ A, int lda,
    const ushortT* __restrict__ BT, int ldb,
    float* __restrict__ C) {
  __shared__ __align__(16) char smem[64 * 128 + 64 * 128];  // 8KB + 8KB
  char* As = smem;
  char* Bs = smem + 64 * 128;
  const int tid = threadIdx.x;
  const int lane = tid & 63;
  const int quad = lane >> 4;
  const int l16 = lane & 15;
  const int wid = tid >> 6;
  const int wm = wid & 1;   // 2 m-halves of 32
  const int wn = wid >> 1;  // 2 n-halves of 32
  const int m0 = blockIdx.y * 64;
  const int n0 = blockIdx.x * 64;

  floatx4 acc[2][2] = {};

  for (int k0 = 0; k0 < DI; k0 += 64) {
    for (int i = tid; i < 64 * 8; i += 256) {
      const int r = i >> 3, c = i & 7;
      const int cg = c ^ (r & 7);
      gl2lds16(A + (size_t)(m0 + r) * lda + k0 + cg * 8, As + (i - lane) * 16);
    }
    for (int i = tid; i < 64 * 8; i += 256) {
      const int r = i >> 3, c = i & 7;
      const int cg = c ^ (r & 7);
      gl2lds16(BT + (size_t)(n0 + r) * ldb + k0 + cg * 8, Bs + (i - lane) * 16);
    }
    __syncthreads();

    short8 afr[2][2], bfr[2][2];
#pragma unroll
    for (int i = 0; i < 2; ++i) {
      const int m = wm * 32 + i * 16 + l16;
#pragma unroll
      for (int s = 0; s < 2; ++s)
        afr[i][s] = *(const short8*)(As + m * 128 + (((s * 4 + quad) ^ (m & 7)) * 16));
    }
#pragma unroll
    for (int j = 0; j < 2; ++j) {
      const int n = wn * 32 + j * 16 + l16;
#pragma unroll
      for (int s = 0; s < 2; ++s)
        bfr[j][s] = *(const short8*)(Bs + n * 128 + (((s * 4 + quad) ^ (n & 7)) * 16));
    }
#pragma unroll
    for (int s = 0; s < 2; ++s)
#pragma unroll
      for (int i = 0; i < 2; ++i)
#pragma unroll
        for (int j = 0; j < 2; ++j)
          acc[i][j] = __builtin_amdgcn_mfma_f32_16x16x32_bf16(afr[i][s], bfr[j][s],
                                                              acc[i][j], 0, 0, 0);
    __syncthreads();
  }
#pragma unroll
  for (int i = 0; i < 2; ++i)
#pragma unroll
    for (int j = 0; j < 2; ++j)
#pragma unroll
      for (int r = 0; r < 4; ++r) {
        const int m = m0 + wm * 32 + i * 16 + quad * 4 + r;
        const int n = n0 + wn * 32 + j * 16 + l16;
        C[(size_t)m * DM + n] = acc[i][j][r];
      }
}

// ------------- x_dbl partials: xc(bf16) @ Wx (padded N=128), K-split via MFMA -------------
__global__ __launch_bounds__(256) void gemm_xdbl_mfma(
    const ushortT* __restrict__ xcb, const ushortT* __restrict__ WxT,
    float* __restrict__ part) {
  __shared__ __align__(16) char smem[64 * 64 + 128 * 64];
  char* As = smem;             // [64 r][64 B bf16]
  char* Bs = smem + 64 * 64;   // [128 r][64 B bf16]
  const int tid = threadIdx.x;
  const int lane = tid & 63;
  const int quad = lane >> 4;
  const int l16 = lane & 15;
  const int wid = tid >> 6;
  const int wm = wid & 1;
  const int wn = wid >> 1;
  const int m0 = blockIdx.x * 64;
  const int kbase = blockIdx.y * (DI / KSPLIT);

  floatx4 acc[2][4] = {};

  for (int kk = 0; kk < DI / KSPLIT; kk += 32) {
    const int k0 = kbase + kk;
    for (int i = tid; i < 64 * 4; i += 256) {
      const int r = i >> 2, c = i & 3;
      const int cg = c ^ (r & 3);
      gl2lds16(xcb + (size_t)(m0 + r) * DI + k0 + cg * 8, As + (i - lane) * 16);
    }
    for (int i = tid; i < 128 * 4; i += 256) {
      const int r = i >> 2, c = i & 3;
      const int cg = c ^ (r & 3);
      gl2lds16(WxT + (size_t)r * DI + k0 + cg * 8, Bs + (i - lane) * 16);
    }
    __syncthreads();

    short8 afr[2], bfr[4];
#pragma unroll
    for (int i = 0; i < 2; ++i) {
      const int m = wm * 32 + i * 16 + l16;
      afr[i] = *(const short8*)(As + m * 64 + ((quad ^ (m & 3)) * 16));
    }
#pragma unroll
    for (int j = 0; j < 4; ++j) {
      const int n = wn * 64 + j * 16 + l16;
      bfr[j] = *(const short8*)(Bs + n * 64 + ((quad ^ (n & 3)) * 16));
    }
#pragma unroll
    for (int i = 0; i < 2; ++i)
#pragma unroll
      for (int j = 0; j < 4; ++j)
        acc[i][j] = __builtin_amdgcn_mfma_f32_16x16x32_bf16(afr[i], bfr[j],
                                                            acc[i][j], 0, 0, 0);
    __syncthreads();
  }
  float* out = part + (size_t)blockIdx.y * (B_SZ * L_SZ * XDLD);
#pragma unroll
  for (int i = 0; i < 2; ++i)
#pragma unroll
    for (int j = 0; j < 4; ++j)
#pragma unroll
      for (int r = 0; r < 4; ++r) {
        const int m = m0 + wm * 32 + i * 16 + quad * 4 + r;
        const int n = wn * 64 + j * 16 + l16;
        out[(size_t)m * XDLD + n] = acc[i][j][r];
      }
}

// ------------- xdbl = sum of KSPLIT partials; also emit dt cols 0..63 as bf16 -------------
__global__ __launch_bounds__(256) void xdbl_reduce(const float* __restrict__ part,
                                                   float* __restrict__ xdbl,
                                                   ushortT* __restrict__ dtb) {
  const int i = blockIdx.x * 256 + threadIdx.x;  // float4 index, [0, 65536)
  float4 a = ((const float4*)part)[i];
#pragma unroll
  for (int s = 1; s < KSPLIT; ++s) {
    const float4 b = ((const float4*)part)[(size_t)s * (B_SZ * L_SZ * XDLD / 4) + i];
    a.x += b.x; a.y += b.y; a.z += b.z; a.w += b.w;
  }
  ((float4*)xdbl)[i] = a;
  // dt = xdbl[:, 0:64] -> compact bf16 [2048][64] for gemm_delta's A operand
  const int row = i >> 5;           // 32 float4 per 128-col row
  const int c4 = (i & 31) * 4;      // column of this float4
  if (c4 < DTR) {
    const unsigned lo = (unsigned)f2bf(a.x) | ((unsigned)f2bf(a.y) << 16);
    const unsigned hi = (unsigned)f2bf(a.z) | ((unsigned)f2bf(a.w) << 16);
    ((uint2*)dtb)[row * (DTR / 4) + (c4 >> 2)] = make_uint2(lo, hi);
  }
}

// ------------- causal depthwise conv (k=4) + silu -> xc bf16 (8-row tiles) -------------
__global__ __launch_bounds__(256) void conv_silu(
    const float* __restrict__ xz, const float* __restrict__ kern,
    const float* __restrict__ bias, ushortT* __restrict__ xcb) {
  const int d = blockIdx.y * 256 + threadIdx.x;
  const int b = blockIdx.x >> 7;           // 128 8-row chunks per batch
  const int l0 = (blockIdx.x & 127) * 8;
  const int row0 = b * L_SZ + l0;
  const float k0v = kern[0 * DI + d], k1v = kern[1 * DI + d];
  const float k2v = kern[2 * DI + d], k3v = kern[3 * DI + d];
  float xv[11];
#pragma unroll
  for (int i = 0; i < 11; ++i) {
    const int l = l0 - 3 + i;
    xv[i] = (l >= 0) ? xz[((size_t)(b * L_SZ + l)) * 4096 + d] : 0.f;
  }
  const float bs = bias[d];
#pragma unroll
  for (int j = 0; j < 8; ++j) {
    float a = bs;
    a = fmaf(xv[j], k0v, a);
    a = fmaf(xv[j + 1], k1v, a);
    a = fmaf(xv[j + 2], k2v, a);
    a = fmaf(xv[j + 3], k3v, a);
    xcb[(size_t)(row0 + j) * DI + d] = f2bf(a / (1.f + __expf(-a)));
  }
}

// ------------- delta = softplus(dt @ Wdt + dt_bias), pure bf16, single K=64 stage -------------
__global__ __launch_bounds__(256) void gemm_delta_mfma(
    const ushortT* __restrict__ dtb, const ushortT* __restrict__ WdtT,
    const float* __restrict__ dt_bias, float* __restrict__ delta) {
  __shared__ __align__(16) char smem[64 * 128 + 64 * 128];  // A 8KB | B 8KB
  char* As = smem;
  char* Bs = smem + 64 * 128;
  const int tid = threadIdx.x;
  const int lane = tid & 63;
  const int quad = lane >> 4;
  const int l16 = lane & 15;
  const int wid = tid >> 6;
  const int wm = wid & 1;
  const int wn = wid >> 1;
  const int m0 = blockIdx.x * 64;
  const int n0 = blockIdx.y * 64;

  // Stage A (dt bf16 [64][64]) and B (WdtT [64][64]) — full K=64, one shot.
  for (int i = tid; i < 64 * 8; i += 256) {
    const int r = i >> 3, c = i & 7;
    const int cg = c ^ (r & 7);
    gl2lds16(dtb + (size_t)(m0 + r) * DTR + cg * 8, As + (i - lane) * 16);
  }
  for (int i = tid; i < 64 * 8; i += 256) {
    const int r = i >> 3, c = i & 7;
    const int cg = c ^ (r & 7);
    gl2lds16(WdtT + (size_t)(n0 + r) * DTR + cg * 8, Bs + (i - lane) * 16);
  }
  __syncthreads();

  floatx4 acc[2][2] = {};
  short8 afr[2][2], bfr[2][2];
#pragma unroll
  for (int i = 0; i < 2; ++i) {
    const int m = wm * 32 + i * 16 + l16;
#pragma unroll
    for (int s = 0; s < 2; ++s)
      afr[i][s] = *(const short8*)(As + m * 128 + (((s * 4 + quad) ^ (m & 7)) * 16));
  }
#pragma unroll
  for (int j = 0; j < 2; ++j) {
    const int n = wn * 32 + j * 16 + l16;
#pragma unroll
    for (int s = 0; s < 2; ++s)
      bfr[j][s] = *(const short8*)(Bs + n * 128 + (((s * 4 + quad) ^ (n & 7)) * 16));
  }
#pragma unroll
  for (int s = 0; s < 2; ++s)
#pragma unroll
    for (int i = 0; i < 2; ++i)
#pragma unroll
      for (int j = 0; j < 2; ++j)
        acc[i][j] = __builtin_amdgcn_mfma_f32_16x16x32_bf16(afr[i][s], bfr[j][s],
                                                            acc[i][j], 0, 0, 0);

#pragma unroll
  for (int i = 0; i < 2; ++i)
#pragma unroll
    for (int j = 0; j < 2; ++j) {
      const int n = n0 + wn * 32 + j * 16 + l16;
      const float bias = dt_bias[n];
#pragma unroll
      for (int r = 0; r < 4; ++r) {
        const int m = m0 + wm * 32 + i * 16 + quad * 4 + r;
        const float a = acc[i][j][r] + bias;
        // softplus: a>20 guard covers overflow; expf underflow -> log(1)=0 is exact.
        delta[(size_t)m * DI + n] = (a > 20.f) ? a : __logf(1.f + __expf(a));
      }
    }
}

// ------------- scan phase 1: per-chunk transition -------------
// 2048 blocks x 256 thr (32 waves/CU): block = (b, chunk c, 32 d's); 8 thr/d, 2 states.
// P computed once per chunk as exp2(Av2 * sum(delta)) — mathematically = per-step product.
__global__ __launch_bounds__(256) void scan_phase1(
    const float* __restrict__ delta, const ushortT* __restrict__ xcb,
    const float* __restrict__ xdbl, const float* __restrict__ A_log,
    float* __restrict__ xz) {
  const int bx = blockIdx.x;
  const int b = bx >> 10;
  const int c = (bx >> 6) & 15;
  const int dt = bx & 63;
  const int tid = threadIdx.x;
  const int dl = tid >> 3, nq = tid & 7;
  const int d = dt * 32 + dl;
  const int row0 = b * L_SZ + c * CLEN;

  __shared__ float Bsh[CLEN][16];
  for (int i = tid; i < CLEN * 16; i += 256)
    Bsh[i >> 4][i & 15] = xdbl[(size_t)(row0 + (i >> 4)) * XDLD + 64 + (i & 15)];

  // A with log2(e) folded: dA = exp2(delta * Av2)
  float Av2[2];
#pragma unroll
  for (int j = 0; j < 2; ++j)
    Av2[j] = -__expf(A_log[d * 16 + nq * 2 + j]) * 1.44269504f;

  const float* dp = delta + (size_t)row0 * DI + d;
  const ushortT* up = xcb + (size_t)row0 * DI + d;

  float dB[8], uB[8];
#pragma unroll
  for (int j = 0; j < 8; ++j) {
    dB[j] = dp[(size_t)j * DI];
    uB[j] = bf2f(up[(size_t)j * DI]);
  }
  float x0 = 0.f, x1 = 0.f, sd = 0.f;
  __syncthreads();

#pragma unroll 1
  for (int g = 0; g < 8; ++g) {
    float dN[8] = {}, uN[8] = {};
    if (g + 1 < 8) {
      const int nr = (g + 1) * 8;
#pragma unroll
      for (int j = 0; j < 8; ++j) {
        dN[j] = dp[(size_t)(nr + j) * DI];
        uN[j] = bf2f(up[(size_t)(nr + j) * DI]);
      }
    }
#pragma unroll
    for (int j = 0; j < 8; ++j) {
      const float dlt = dB[j];
      const float2 Bv = *(const float2*)&Bsh[g * 8 + j][nq * 2];
      sd += dlt;
      const float t = dlt * uB[j];
      x0 = fmaf(fexp2(dlt * Av2[0]), x0, t * Bv.x);
      x1 = fmaf(fexp2(dlt * Av2[1]), x1, t * Bv.y);
    }
#pragma unroll
    for (int j = 0; j < 8; ++j) { dB[j] = dN[j]; uB[j] = uN[j]; }
  }
  const unsigned e = ((unsigned)((b * NCHUNK + c) * DI + d)) * 16 + nq * 2;
  *(float2*)&xz[stash_addr(e)] = make_float2(fexp2(Av2[0] * sd), fexp2(Av2[1] * sd));
  *(float2*)&xz[stash_addr((1u << 20) + e)] = make_float2(x0, x1);
}

// ------------- scan phase 3: chunk-init combine + rescan + y + skip + gate -> bf16 y -------
// Same 2048x256 mapping; y-reduce = 3-shuffle tree over the 8 nq lanes; lane nq owns
// output row g*8+nq of each 8-step group (gate cost amortized /8).
__global__ __launch_bounds__(256) void scan_phase3(
    const float* __restrict__ delta, const ushortT* __restrict__ xcb,
    const float* __restrict__ xdbl, const float* __restrict__ A_log,
    const float* __restrict__ Dskip, float* __restrict__ xz) {
  const int bx = blockIdx.x;
  const int b = bx >> 10;
  const int c = (bx >> 6) & 15;
  const int dt = bx & 63;
  const int tid = threadIdx.x;
  const int dl = tid >> 3, nq = tid & 7;
  const int d = dt * 32 + dl;
  const int row0 = b * L_SZ + c * CLEN;

  __shared__ float Bsh[CLEN][16], Csh[CLEN][16];
  for (int i = tid; i < CLEN * 32; i += 256) {
    const int r = i >> 5, q = i & 31;
    const float v = xdbl[(size_t)(row0 + r) * XDLD + 64 + q];
    if (q < 16) Bsh[r][q] = v; else Csh[r][q - 16] = v;
  }

  float Av2[2];
#pragma unroll
  for (int j = 0; j < 2; ++j)
    Av2[j] = -__expf(A_log[d * 16 + nq * 2 + j]) * 1.44269504f;
  const float Dsk = Dskip[d];

  // chunk-init: combine P/S of chunks < c (was scan_phase2) — identical fma order.
  float x0 = 0.f, x1 = 0.f;
  for (int cc = 0; cc < c; ++cc) {
    const unsigned e = ((unsigned)((b * NCHUNK + cc) * DI + d)) * 16 + nq * 2;
    const float2 P = *(const float2*)&xz[stash_addr(e)];
    const float2 S = *(const float2*)&xz[stash_addr((1u << 20) + e)];
    x0 = fmaf(P.x, x0, S.x);
    x1 = fmaf(P.y, x1, S.y);
  }
  __syncthreads();

  const float* dp = delta + (size_t)row0 * DI + d;
  const ushortT* up = xcb + (size_t)row0 * DI + d;
  const float* zp = xz + (size_t)row0 * 4096 + DI + d;
  ushortT* yb = (ushortT*)xz;

  float dB[8], uB[8];
#pragma unroll
  for (int j = 0; j < 8; ++j) {
    dB[j] = dp[(size_t)j * DI];
    uB[j] = bf2f(up[(size_t)j * DI]);
  }
  float zB = zp[(size_t)nq * 4096];

#pragma unroll 1
  for (int g = 0; g < 8; ++g) {
    float dN[8] = {}, uN[8] = {}, zN = 0.f;
    if (g + 1 < 8) {
      const int nr = (g + 1) * 8;
#pragma unroll
      for (int j = 0; j < 8; ++j) {
        dN[j] = dp[(size_t)(nr + j) * DI];
        uN[j] = bf2f(up[(size_t)(nr + j) * DI]);
      }
      zN = zp[(size_t)(nr + nq) * 4096];
    }
    float yk = 0.f, uk = 0.f;
#pragma unroll
    for (int j = 0; j < 8; ++j) {
      const float dlt = dB[j];
      const float u = uB[j];
      const float2 Bv = *(const float2*)&Bsh[g * 8 + j][nq * 2];
      const float2 Cv = *(const float2*)&Csh[g * 8 + j][nq * 2];
      const float t = dlt * u;
      x0 = fmaf(fexp2(dlt * Av2[0]), x0, t * Bv.x);
      x1 = fmaf(fexp2(dlt * Av2[1]), x1, t * Bv.y);
      float y = fmaf(x1, Cv.y, x0 * Cv.x);
      y += __shfl_xor(y, 1);
      y += __shfl_xor(y, 2);
      y += __shfl_xor(y, 4);
      if (nq == j) { yk = y; uk = u; }
    }
    const float sig = zB / (1.f + __expf(-zB));
    yb[(size_t)(row0 + g * 8 + nq) * 8192 + d] = f2bf(fmaf(uk, Dsk, yk) * sig);
#pragma unroll
    for (int j = 0; j < 8; ++j) { dB[j] = dN[j]; uB[j] = uN[j]; }
    zB = zN;
  }
}

extern "C" void kernel_launch(void* const* d_in, const int* in_sizes, int n_in,
                              void* d_out, int out_size, void* d_ws, size_t ws_size,
                              hipStream_t stream) {
  const float* hidden  = (const float*)d_in[0];
  const float* Win     = (const float*)d_in[1];
  const float* Wx      = (const float*)d_in[2];
  const float* Wdt     = (const float*)d_in[3];
  const float* dt_bias = (const float*)d_in[4];
  const float* Wout    = (const float*)d_in[5];
  const float* dwk     = (const float*)d_in[6];
  const float* dwb     = (const float*)d_in[7];
  const float* A_log   = (const float*)d_in[8];
  const float* Dskip   = (const float*)d_in[9];

  // ws (64 MB): xz 32MB | shared16 (WinT -> xdbl partials -> delta) 16MB
  //             | [48,56M) xcb bf16 | [56,60M) WoutT bf16 | [60,64M) free
  // xz per-row float layout: [0,1024) y-bf16 | [1024,2048) scan stash | [2048,4096) z
  char* ws = (char*)d_ws;
  float* xz       = (float*)ws;
  float* shared16 = (float*)(ws + (32u << 20));
  ushortT* xcb    = (ushortT*)(ws + (48u << 20));
  ushortT* WoutT  = (ushortT*)(ws + (56u << 20));
  // d_out (8 MB) scratch: hidb [0,4M) (dead after GEMM1); xdbl128 [4M,5M);
  //                       WxT [5M,5.5M); WdtT [5.5M,5.75M); dtb [5.75M,6M)
  // all dead before gemm_out overwrites d_out with the final result.
  char* dob = (char*)d_out;
  ushortT* hidb = (ushortT*)dob;
  float* xdbl   = (float*)(dob + (4u << 20));
  ushortT* WxT  = (ushortT*)(dob + (5u << 20));
  ushortT* WdtT = (ushortT*)(dob + (5u << 20) + (512u << 10));
  ushortT* dtb  = (ushortT*)(dob + (5u << 20) + (768u << 10));

  // 1. fused prep: hidden->bf16, Win^T, Wx pad^T, Wdt^T, Wout^T
  prep_all<<<dim3(9344), 256, 0, stream>>>(hidden, hidb, Win, (ushortT*)shared16,
                                           Wx, WxT, Wdt, WdtT, Wout, WoutT);
  // 2. GEMM1: xz = hidden @ Win  (M=2048, N=4096, K=1024); 128x128, 8 waves, 512 blocks
  gemm1_big<<<dim3(4096 / 128, 2048 / 128), 512, 0, stream>>>(
      hidb, DM, (ushortT*)shared16, DM, xz, 2 * DI, DM);
  // 3. depthwise conv + silu -> xc bf16 (8-row tiles)
  conv_silu<<<dim3(B_SZ * L_SZ / 8, DI / 256), 256, 0, stream>>>(xz, dwk, dwb, xcb);
  // 4. x_dbl partials (K-split 8) -> shared16 [0,8M) (WinT dead), then reduce (+dt bf16)
  gemm_xdbl_mfma<<<dim3(B_SZ * L_SZ / 64, KSPLIT), 256, 0, stream>>>(
      xcb, WxT, shared16);
  xdbl_reduce<<<dim3(B_SZ * L_SZ * XDLD / 1024), 256, 0, stream>>>(shared16, xdbl, dtb);
  // 5. delta = softplus(dt @ Wdt + bias): pure-bf16 MFMA, single K=64 stage, 1024 blocks
  gemm_delta_mfma<<<dim3(B_SZ * L_SZ / 64, DI / 64), 256, 0, stream>>>(
      dtb, WdtT, dt_bias, shared16);
  // 6-7. chunked selective scan, 32-waves/CU variant; phase3 folds the chunk combine
  scan_phase1<<<dim3(2048), 256, 0, stream>>>(
      shared16, xcb, xdbl, A_log, xz);
  scan_phase3<<<dim3(2048), 256, 0, stream>>>(
      shared16, xcb, xdbl, A_log, Dskip, xz);
  // 8. GEMM4: out = y @ Wout (M=2048, N=1024, K=2048), direct write to d_out
  gemm_out<<<dim3(DM / 64, 2048 / 64), 256, 0, stream>>>(
      (ushortT*)xz, 4 * DI, WoutT, DI, (float*)d_out);
}

// Round 6
// 224.641 us; speedup vs baseline: 1.5885x; 1.0096x over previous
//
#include <hip/hip_runtime.h>
#include <hip/hip_bf16.h>
#include <math.h>

#define B_SZ 2
#define L_SZ 1024
#define DM 1024
#define DI 2048
#define NS 16
#define DTR 64
#define NCHUNK 16
#define CLEN 64
#define XDLD 128  // padded x_dbl leading dim
#define KSPLIT 8

typedef unsigned short ushortT;
typedef __attribute__((ext_vector_type(8))) short short8;
typedef __attribute__((ext_vector_type(4))) float floatx4;

__device__ __forceinline__ ushortT f2bf(float f) {
  unsigned u = __float_as_uint(f);
  unsigned r = (u + 0x7fff + ((u >> 16) & 1)) >> 16;
  return (ushortT)r;
}

__device__ __forceinline__ float bf2f(ushortT v) {
  return __uint_as_float((unsigned)v << 16);
}

__device__ __forceinline__ float fexp2(float x) {
  float r;
  asm("v_exp_f32 %0, %1" : "=v"(r) : "v"(x));
  return r;
}

__device__ __forceinline__ void gl2lds16(const void* g, void* l) {
  __builtin_amdgcn_global_load_lds(
      (const __attribute__((address_space(1))) unsigned int*)g,
      (__attribute__((address_space(3))) unsigned int*)l, 16, 0, 0);
}

// Scan-state stash lives in the dead strided region of xz: floats [1024,2048)
// of each 4096-float row. i in [0, 2M): aprod at i, sfin at i + 1M.
__device__ __forceinline__ unsigned stash_addr(unsigned i) {
  return (i >> 10) * 4096 + 1024 + (i & 1023);
}

// ---------------- fused prep: cvt + 3 transposes + wx_pad ----------------
__device__ __forceinline__ void tr_body(const float* __restrict__ src,
                                        ushortT* __restrict__ dst, int R, int C,
                                        int bx, int by, int tx, int ty,
                                        float (*t)[33]) {
#pragma unroll
  for (int j = 0; j < 4; ++j)
    t[ty + j * 8][tx] = src[(size_t)(by + ty + j * 8) * C + bx + tx];
  __syncthreads();
#pragma unroll
  for (int j = 0; j < 4; ++j)
    dst[(size_t)(bx + ty + j * 8) * R + by + tx] = f2bf(t[tx][ty + j * 8]);
}

// grid ranges: [0,2048) cvt hidden | [2048,6144) Win-T | [6144,7168) Wx pad-T
//              [7168,7296) Wdt-T | [7296,9344) Wout-T
__global__ __launch_bounds__(256) void prep_all(
    const float* __restrict__ hidden, ushortT* __restrict__ hidb,
    const float* __restrict__ Win, ushortT* __restrict__ WinT,
    const float* __restrict__ Wx, ushortT* __restrict__ WxT,
    const float* __restrict__ Wdt, ushortT* __restrict__ WdtT,
    const float* __restrict__ Wout, ushortT* __restrict__ WoutT) {
  __shared__ float t[32][33];
  const int blk = blockIdx.x;
  const int tid = threadIdx.x;
  const int tx = tid & 31, ty = tid >> 5;
  if (blk < 2048) {
    const int i = blk * 256 + tid;
    float4 v = ((const float4*)hidden)[i];
    unsigned lo = (unsigned)f2bf(v.x) | ((unsigned)f2bf(v.y) << 16);
    unsigned hi = (unsigned)f2bf(v.z) | ((unsigned)f2bf(v.w) << 16);
    ((uint2*)hidb)[i] = make_uint2(lo, hi);
  } else if (blk < 6144) {
    const int rel = blk - 2048;  // (128, 32): C=4096, R=1024
    tr_body(Win, WinT, DM, 2 * DI, (rel & 127) * 32, (rel >> 7) * 32, tx, ty, t);
  } else if (blk < 7168) {
    const int rel = blk - 6144;  // (8, 128)
    const int k = (rel & 7) * 256 + tid;
    const int n = rel >> 3;
    WxT[(size_t)n * DI + k] = (n < 96) ? f2bf(Wx[(size_t)k * 96 + n]) : (ushortT)0;
  } else if (blk < 7296) {
    const int rel = blk - 7168;  // (64, 2): C=2048, R=64
    tr_body(Wdt, WdtT, DTR, DI, (rel & 63) * 32, (rel >> 6) * 32, tx, ty, t);
  } else {
    const int rel = blk - 7296;  // (32, 64): C=1024, R=2048
    tr_body(Wout, WoutT, DI, DM, (rel & 31) * 32, (rel >> 5) * 32, tx, ty, t);
  }
}

// ---------------- GEMM1: 128x128 tile, BK=64, 8 waves (512 thr), 512 blocks ----------------
__global__ __launch_bounds__(512) void gemm1_big(
    const ushortT* __restrict__ A, int lda,
    const ushortT* __restrict__ BT, int ldb,
    float* __restrict__ C, int ldc, int K) {
  __shared__ __align__(16) char smem[128 * 128 + 128 * 128];  // A 16KB | B 16KB
  char* As = smem;
  char* Bs = smem + 128 * 128;
  const int tid = threadIdx.x;
  const int lane = tid & 63;
  const int quad = lane >> 4;
  const int l16 = lane & 15;
  const int wid = tid >> 6;
  const int wm = wid & 1;   // 2 m-halves of 64
  const int wn = wid >> 1;  // 4 n-quarters of 32
  const int m0 = blockIdx.y * 128;
  const int n0 = blockIdx.x * 128;

  floatx4 acc[4][2] = {};

  for (int k0 = 0; k0 < K; k0 += 64) {
    for (int i = tid; i < 128 * 8; i += 512) {
      const int r = i >> 3, c = i & 7;
      const int cg = c ^ (r & 7);
      gl2lds16(A + (size_t)(m0 + r) * lda + k0 + cg * 8, As + (i - lane) * 16);
    }
    for (int i = tid; i < 128 * 8; i += 512) {
      const int r = i >> 3, c = i & 7;
      const int cg = c ^ (r & 7);
      gl2lds16(BT + (size_t)(n0 + r) * ldb + k0 + cg * 8, Bs + (i - lane) * 16);
    }
    __syncthreads();

    short8 afr[4][2], bfr[2][2];
#pragma unroll
    for (int i = 0; i < 4; ++i) {
      const int r = wm * 64 + i * 16 + l16;
#pragma unroll
      for (int s = 0; s < 2; ++s)
        afr[i][s] = *(const short8*)(As + r * 128 + (((s * 4 + quad) ^ (r & 7)) * 16));
    }
#pragma unroll
    for (int j = 0; j < 2; ++j) {
      const int r = wn * 32 + j * 16 + l16;
#pragma unroll
      for (int s = 0; s < 2; ++s)
        bfr[j][s] = *(const short8*)(Bs + r * 128 + (((s * 4 + quad) ^ (r & 7)) * 16));
    }
#pragma unroll
    for (int s = 0; s < 2; ++s)
#pragma unroll
      for (int i = 0; i < 4; ++i)
#pragma unroll
        for (int j = 0; j < 2; ++j)
          acc[i][j] = __builtin_amdgcn_mfma_f32_16x16x32_bf16(afr[i][s], bfr[j][s],
                                                              acc[i][j], 0, 0, 0);
    __syncthreads();
  }
#pragma unroll
  for (int i = 0; i < 4; ++i)
#pragma unroll
    for (int j = 0; j < 2; ++j)
#pragma unroll
      for (int r = 0; r < 4; ++r) {
        const int m = m0 + wm * 64 + i * 16 + quad * 4 + r;
        const int n = n0 + wn * 32 + j * 16 + l16;
        C[(size_t)m * ldc + n] = acc[i][j][r];
      }
}

// ---------------- GEMM4: 64x64 tile, BK=64, K=2048, 4 waves, 512 blocks, direct out --------
__global__ __launch_bounds__(256) void gemm_out(
    const ushortT* __restrict__ A, int lda,
    const ushortT* __restrict__ BT, int ldb,
    float* __restrict__ C) {
  __shared__ __align__(16) char smem[64 * 128 + 64 * 128];  // 8KB + 8KB
  char* As = smem;
  char* Bs = smem + 64 * 128;
  const int tid = threadIdx.x;
  const int lane = tid & 63;
  const int quad = lane >> 4;
  const int l16 = lane & 15;
  const int wid = tid >> 6;
  const int wm = wid & 1;   // 2 m-halves of 32
  const int wn = wid >> 1;  // 2 n-halves of 32
  const int m0 = blockIdx.y * 64;
  const int n0 = blockIdx.x * 64;

  floatx4 acc[2][2] = {};

  for (int k0 = 0; k0 < DI; k0 += 64) {
    for (int i = tid; i < 64 * 8; i += 256) {
      const int r = i >> 3, c = i & 7;
      const int cg = c ^ (r & 7);
      gl2lds16(A + (size_t)(m0 + r) * lda + k0 + cg * 8, As + (i - lane) * 16);
    }
    for (int i = tid; i < 64 * 8; i += 256) {
      const int r = i >> 3, c = i & 7;
      const int cg = c ^ (r & 7);
      gl2lds16(BT + (size_t)(n0 + r) * ldb + k0 + cg * 8, Bs + (i - lane) * 16);
    }
    __syncthreads();

    short8 afr[2][2], bfr[2][2];
#pragma unroll
    for (int i = 0; i < 2; ++i) {
      const int m = wm * 32 + i * 16 + l16;
#pragma unroll
      for (int s = 0; s < 2; ++s)
        afr[i][s] = *(const short8*)(As + m * 128 + (((s * 4 + quad) ^ (m & 7)) * 16));
    }
#pragma unroll
    for (int j = 0; j < 2; ++j) {
      const int n = wn * 32 + j * 16 + l16;
#pragma unroll
      for (int s = 0; s < 2; ++s)
        bfr[j][s] = *(const short8*)(Bs + n * 128 + (((s * 4 + quad) ^ (n & 7)) * 16));
    }
#pragma unroll
    for (int s = 0; s < 2; ++s)
#pragma unroll
      for (int i = 0; i < 2; ++i)
#pragma unroll
        for (int j = 0; j < 2; ++j)
          acc[i][j] = __builtin_amdgcn_mfma_f32_16x16x32_bf16(afr[i][s], bfr[j][s],
                                                              acc[i][j], 0, 0, 0);
    __syncthreads();
  }
#pragma unroll
  for (int i = 0; i < 2; ++i)
#pragma unroll
    for (int j = 0; j < 2; ++j)
#pragma unroll
      for (int r = 0; r < 4; ++r) {
        const int m = m0 + wm * 32 + i * 16 + quad * 4 + r;
        const int n = n0 + wn * 32 + j * 16 + l16;
        C[(size_t)m * DM + n] = acc[i][j][r];
      }
}

// ------------- x_dbl partials: xc(bf16) @ Wx (padded N=128), K-split via MFMA -------------
__global__ __launch_bounds__(256) void gemm_xdbl_mfma(
    const ushortT* __restrict__ xcb, const ushortT* __restrict__ WxT,
    float* __restrict__ part) {
  __shared__ __align__(16) char smem[64 * 64 + 128 * 64];
  char* As = smem;             // [64 r][64 B bf16]
  char* Bs = smem + 64 * 64;   // [128 r][64 B bf16]
  const int tid = threadIdx.x;
  const int lane = tid & 63;
  const int quad = lane >> 4;
  const int l16 = lane & 15;
  const int wid = tid >> 6;
  const int wm = wid & 1;
  const int wn = wid >> 1;
  const int m0 = blockIdx.x * 64;
  const int kbase = blockIdx.y * (DI / KSPLIT);

  floatx4 acc[2][4] = {};

  for (int kk = 0; kk < DI / KSPLIT; kk += 32) {
    const int k0 = kbase + kk;
    for (int i = tid; i < 64 * 4; i += 256) {
      const int r = i >> 2, c = i & 3;
      const int cg = c ^ (r & 3);
      gl2lds16(xcb + (size_t)(m0 + r) * DI + k0 + cg * 8, As + (i - lane) * 16);
    }
    for (int i = tid; i < 128 * 4; i += 256) {
      const int r = i >> 2, c = i & 3;
      const int cg = c ^ (r & 3);
      gl2lds16(WxT + (size_t)r * DI + k0 + cg * 8, Bs + (i - lane) * 16);
    }
    __syncthreads();

    short8 afr[2], bfr[4];
#pragma unroll
    for (int i = 0; i < 2; ++i) {
      const int m = wm * 32 + i * 16 + l16;
      afr[i] = *(const short8*)(As + m * 64 + ((quad ^ (m & 3)) * 16));
    }
#pragma unroll
    for (int j = 0; j < 4; ++j) {
      const int n = wn * 64 + j * 16 + l16;
      bfr[j] = *(const short8*)(Bs + n * 64 + ((quad ^ (n & 3)) * 16));
    }
#pragma unroll
    for (int i = 0; i < 2; ++i)
#pragma unroll
      for (int j = 0; j < 4; ++j)
        acc[i][j] = __builtin_amdgcn_mfma_f32_16x16x32_bf16(afr[i], bfr[j],
                                                            acc[i][j], 0, 0, 0);
    __syncthreads();
  }
  float* out = part + (size_t)blockIdx.y * (B_SZ * L_SZ * XDLD);
#pragma unroll
  for (int i = 0; i < 2; ++i)
#pragma unroll
    for (int j = 0; j < 4; ++j)
#pragma unroll
      for (int r = 0; r < 4; ++r) {
        const int m = m0 + wm * 32 + i * 16 + quad * 4 + r;
        const int n = wn * 64 + j * 16 + l16;
        out[(size_t)m * XDLD + n] = acc[i][j][r];
      }
}

// ------------- xdbl = sum of KSPLIT partials; also emit dt cols 0..63 as bf16 -------------
__global__ __launch_bounds__(256) void xdbl_reduce(const float* __restrict__ part,
                                                   float* __restrict__ xdbl,
                                                   ushortT* __restrict__ dtb) {
  const int i = blockIdx.x * 256 + threadIdx.x;  // float4 index, [0, 65536)
  float4 a = ((const float4*)part)[i];
#pragma unroll
  for (int s = 1; s < KSPLIT; ++s) {
    const float4 b = ((const float4*)part)[(size_t)s * (B_SZ * L_SZ * XDLD / 4) + i];
    a.x += b.x; a.y += b.y; a.z += b.z; a.w += b.w;
  }
  ((float4*)xdbl)[i] = a;
  // dt = xdbl[:, 0:64] -> compact bf16 [2048][64] for gemm_delta's A operand
  const int row = i >> 5;           // 32 float4 per 128-col row
  const int c4 = (i & 31) * 4;      // column of this float4
  if (c4 < DTR) {
    const unsigned lo = (unsigned)f2bf(a.x) | ((unsigned)f2bf(a.y) << 16);
    const unsigned hi = (unsigned)f2bf(a.z) | ((unsigned)f2bf(a.w) << 16);
    ((uint2*)dtb)[row * (DTR / 4) + (c4 >> 2)] = make_uint2(lo, hi);
  }
}

// ------------- causal depthwise conv (k=4) + silu -> xc bf16 (8-row tiles) -------------
__global__ __launch_bounds__(256) void conv_silu(
    const float* __restrict__ xz, const float* __restrict__ kern,
    const float* __restrict__ bias, ushortT* __restrict__ xcb) {
  const int d = blockIdx.y * 256 + threadIdx.x;
  const int b = blockIdx.x >> 7;           // 128 8-row chunks per batch
  const int l0 = (blockIdx.x & 127) * 8;
  const int row0 = b * L_SZ + l0;
  const float k0v = kern[0 * DI + d], k1v = kern[1 * DI + d];
  const float k2v = kern[2 * DI + d], k3v = kern[3 * DI + d];
  float xv[11];
#pragma unroll
  for (int i = 0; i < 11; ++i) {
    const int l = l0 - 3 + i;
    xv[i] = (l >= 0) ? xz[((size_t)(b * L_SZ + l)) * 4096 + d] : 0.f;
  }
  const float bs = bias[d];
#pragma unroll
  for (int j = 0; j < 8; ++j) {
    float a = bs;
    a = fmaf(xv[j], k0v, a);
    a = fmaf(xv[j + 1], k1v, a);
    a = fmaf(xv[j + 2], k2v, a);
    a = fmaf(xv[j + 3], k3v, a);
    xcb[(size_t)(row0 + j) * DI + d] = f2bf(a / (1.f + __expf(-a)));
  }
}

// ------------- delta = softplus(dt @ Wdt + dt_bias), pure bf16, single K=64 stage -------------
__global__ __launch_bounds__(256) void gemm_delta_mfma(
    const ushortT* __restrict__ dtb, const ushortT* __restrict__ WdtT,
    const float* __restrict__ dt_bias, float* __restrict__ delta) {
  __shared__ __align__(16) char smem[64 * 128 + 64 * 128];  // A 8KB | B 8KB
  char* As = smem;
  char* Bs = smem + 64 * 128;
  const int tid = threadIdx.x;
  const int lane = tid & 63;
  const int quad = lane >> 4;
  const int l16 = lane & 15;
  const int wid = tid >> 6;
  const int wm = wid & 1;
  const int wn = wid >> 1;
  const int m0 = blockIdx.x * 64;
  const int n0 = blockIdx.y * 64;

  // Stage A (dt bf16 [64][64]) and B (WdtT [64][64]) — full K=64, one shot.
  for (int i = tid; i < 64 * 8; i += 256) {
    const int r = i >> 3, c = i & 7;
    const int cg = c ^ (r & 7);
    gl2lds16(dtb + (size_t)(m0 + r) * DTR + cg * 8, As + (i - lane) * 16);
  }
  for (int i = tid; i < 64 * 8; i += 256) {
    const int r = i >> 3, c = i & 7;
    const int cg = c ^ (r & 7);
    gl2lds16(WdtT + (size_t)(n0 + r) * DTR + cg * 8, Bs + (i - lane) * 16);
  }
  __syncthreads();

  floatx4 acc[2][2] = {};
  short8 afr[2][2], bfr[2][2];
#pragma unroll
  for (int i = 0; i < 2; ++i) {
    const int m = wm * 32 + i * 16 + l16;
#pragma unroll
    for (int s = 0; s < 2; ++s)
      afr[i][s] = *(const short8*)(As + m * 128 + (((s * 4 + quad) ^ (m & 7)) * 16));
  }
#pragma unroll
  for (int j = 0; j < 2; ++j) {
    const int n = wn * 32 + j * 16 + l16;
#pragma unroll
    for (int s = 0; s < 2; ++s)
      bfr[j][s] = *(const short8*)(Bs + n * 128 + (((s * 4 + quad) ^ (n & 7)) * 16));
  }
#pragma unroll
  for (int s = 0; s < 2; ++s)
#pragma unroll
    for (int i = 0; i < 2; ++i)
#pragma unroll
      for (int j = 0; j < 2; ++j)
        acc[i][j] = __builtin_amdgcn_mfma_f32_16x16x32_bf16(afr[i][s], bfr[j][s],
                                                            acc[i][j], 0, 0, 0);

#pragma unroll
  for (int i = 0; i < 2; ++i)
#pragma unroll
    for (int j = 0; j < 2; ++j) {
      const int n = n0 + wn * 32 + j * 16 + l16;
      const float bias = dt_bias[n];
#pragma unroll
      for (int r = 0; r < 4; ++r) {
        const int m = m0 + wm * 32 + i * 16 + quad * 4 + r;
        const float a = acc[i][j][r] + bias;
        // softplus: a>20 guard covers overflow; expf underflow -> log(1)=0 is exact.
        delta[(size_t)m * DI + n] = (a > 20.f) ? a : __logf(1.f + __expf(a));
      }
    }
}

// ------------- scan phase 1: per-chunk transition -------------
// 512 blocks x 256 thr: block = (b, chunk c, 128 d's); 2 thr/d, 8 states each.
// delta/u loaded once per pair (coalesced row-major); no shuffles needed.
// P computed once per chunk as exp2(Av2 * sum(delta)).
__global__ __launch_bounds__(256) void scan_phase1(
    const float* __restrict__ delta, const ushortT* __restrict__ xcb,
    const float* __restrict__ xdbl, const float* __restrict__ A_log,
    float* __restrict__ xz) {
  const int bx = blockIdx.x;
  const int b = bx >> 8;
  const int c = (bx >> 4) & 15;
  const int dblk = bx & 15;
  const int tid = threadIdx.x;
  const int half = tid & 1;           // which 8 of the 16 states
  const int d = dblk * 128 + (tid >> 1);
  const int row0 = b * L_SZ + c * CLEN;

  __shared__ float Bsh[CLEN][16];
  for (int i = tid; i < CLEN * 16; i += 256)
    Bsh[i >> 4][i & 15] = xdbl[(size_t)(row0 + (i >> 4)) * XDLD + 64 + (i & 15)];

  // A with log2(e) folded: dA = exp2(delta * Av2)
  float Av2[8];
  {
    const float4 a0 = *(const float4*)&A_log[d * 16 + half * 8];
    const float4 a1 = *(const float4*)&A_log[d * 16 + half * 8 + 4];
    Av2[0] = -__expf(a0.x) * 1.44269504f;
    Av2[1] = -__expf(a0.y) * 1.44269504f;
    Av2[2] = -__expf(a0.z) * 1.44269504f;
    Av2[3] = -__expf(a0.w) * 1.44269504f;
    Av2[4] = -__expf(a1.x) * 1.44269504f;
    Av2[5] = -__expf(a1.y) * 1.44269504f;
    Av2[6] = -__expf(a1.z) * 1.44269504f;
    Av2[7] = -__expf(a1.w) * 1.44269504f;
  }

  const float* dp = delta + (size_t)row0 * DI + d;
  const ushortT* up = xcb + (size_t)row0 * DI + d;

  float dB[8], uB[8];
#pragma unroll
  for (int j = 0; j < 8; ++j) {
    dB[j] = dp[(size_t)j * DI];
    uB[j] = bf2f(up[(size_t)j * DI]);
  }
  float x[8] = {};
  float sd = 0.f;
  __syncthreads();

#pragma unroll 1
  for (int g = 0; g < 8; ++g) {
    float dN[8] = {}, uN[8] = {};
    if (g + 1 < 8) {
      const int nr = (g + 1) * 8;
#pragma unroll
      for (int j = 0; j < 8; ++j) {
        dN[j] = dp[(size_t)(nr + j) * DI];
        uN[j] = bf2f(up[(size_t)(nr + j) * DI]);
      }
    }
#pragma unroll
    for (int j = 0; j < 8; ++j) {
      const float dlt = dB[j];
      const float t = dlt * uB[j];
      const float4 B0 = *(const float4*)&Bsh[g * 8 + j][half * 8];
      const float4 B1 = *(const float4*)&Bsh[g * 8 + j][half * 8 + 4];
      sd += dlt;
      x[0] = fmaf(fexp2(dlt * Av2[0]), x[0], t * B0.x);
      x[1] = fmaf(fexp2(dlt * Av2[1]), x[1], t * B0.y);
      x[2] = fmaf(fexp2(dlt * Av2[2]), x[2], t * B0.z);
      x[3] = fmaf(fexp2(dlt * Av2[3]), x[3], t * B0.w);
      x[4] = fmaf(fexp2(dlt * Av2[4]), x[4], t * B1.x);
      x[5] = fmaf(fexp2(dlt * Av2[5]), x[5], t * B1.y);
      x[6] = fmaf(fexp2(dlt * Av2[6]), x[6], t * B1.z);
      x[7] = fmaf(fexp2(dlt * Av2[7]), x[7], t * B1.w);
    }
#pragma unroll
    for (int j = 0; j < 8; ++j) { dB[j] = dN[j]; uB[j] = uN[j]; }
  }
  const unsigned e = ((unsigned)((b * NCHUNK + c) * DI + d)) * 16 + half * 8;
  *(float4*)&xz[stash_addr(e)] =
      make_float4(fexp2(Av2[0] * sd), fexp2(Av2[1] * sd),
                  fexp2(Av2[2] * sd), fexp2(Av2[3] * sd));
  *(float4*)&xz[stash_addr(e + 4)] =
      make_float4(fexp2(Av2[4] * sd), fexp2(Av2[5] * sd),
                  fexp2(Av2[6] * sd), fexp2(Av2[7] * sd));
  *(float4*)&xz[stash_addr((1u << 20) + e)] = make_float4(x[0], x[1], x[2], x[3]);
  *(float4*)&xz[stash_addr((1u << 20) + e + 4)] = make_float4(x[4], x[5], x[6], x[7]);
}

// ------------- scan phase 3: chunk-init combine + rescan + y + skip + gate -> bf16 y -------
// Same 2-thr/d mapping; y-reduce = ONE shfl_xor(y,1); even lane gates+stores each step.
__global__ __launch_bounds__(256) void scan_phase3(
    const float* __restrict__ delta, const ushortT* __restrict__ xcb,
    const float* __restrict__ xdbl, const float* __restrict__ A_log,
    const float* __restrict__ Dskip, float* __restrict__ xz) {
  const int bx = blockIdx.x;
  const int b = bx >> 8;
  const int c = (bx >> 4) & 15;
  const int dblk = bx & 15;
  const int tid = threadIdx.x;
  const int half = tid & 1;
  const int d = dblk * 128 + (tid >> 1);
  const int row0 = b * L_SZ + c * CLEN;

  __shared__ float Bsh[CLEN][16], Csh[CLEN][16];
  for (int i = tid; i < CLEN * 32; i += 256) {
    const int r = i >> 5, q = i & 31;
    const float v = xdbl[(size_t)(row0 + r) * XDLD + 64 + q];
    if (q < 16) Bsh[r][q] = v; else Csh[r][q - 16] = v;
  }

  float Av2[8];
  {
    const float4 a0 = *(const float4*)&A_log[d * 16 + half * 8];
    const float4 a1 = *(const float4*)&A_log[d * 16 + half * 8 + 4];
    Av2[0] = -__expf(a0.x) * 1.44269504f;
    Av2[1] = -__expf(a0.y) * 1.44269504f;
    Av2[2] = -__expf(a0.z) * 1.44269504f;
    Av2[3] = -__expf(a0.w) * 1.44269504f;
    Av2[4] = -__expf(a1.x) * 1.44269504f;
    Av2[5] = -__expf(a1.y) * 1.44269504f;
    Av2[6] = -__expf(a1.z) * 1.44269504f;
    Av2[7] = -__expf(a1.w) * 1.44269504f;
  }
  const float Dsk = Dskip[d];

  // chunk-init: combine P/S of chunks < c — ascending cc, same fma order as before.
  float x[8] = {};
  for (int cc = 0; cc < c; ++cc) {
    const unsigned e = ((unsigned)((b * NCHUNK + cc) * DI + d)) * 16 + half * 8;
    const float4 P0 = *(const float4*)&xz[stash_addr(e)];
    const float4 P1 = *(const float4*)&xz[stash_addr(e + 4)];
    const float4 S0 = *(const float4*)&xz[stash_addr((1u << 20) + e)];
    const float4 S1 = *(const float4*)&xz[stash_addr((1u << 20) + e + 4)];
    x[0] = fmaf(P0.x, x[0], S0.x);
    x[1] = fmaf(P0.y, x[1], S0.y);
    x[2] = fmaf(P0.z, x[2], S0.z);
    x[3] = fmaf(P0.w, x[3], S0.w);
    x[4] = fmaf(P1.x, x[4], S1.x);
    x[5] = fmaf(P1.y, x[5], S1.y);
    x[6] = fmaf(P1.z, x[6], S1.z);
    x[7] = fmaf(P1.w, x[7], S1.w);
  }
  __syncthreads();

  const float* dp = delta + (size_t)row0 * DI + d;
  const ushortT* up = xcb + (size_t)row0 * DI + d;
  const float* zp = xz + (size_t)row0 * 4096 + DI + d;
  ushortT* yb = (ushortT*)xz;

  float dB[8], uB[8], zB[8];
#pragma unroll
  for (int j = 0; j < 8; ++j) {
    dB[j] = dp[(size_t)j * DI];
    uB[j] = bf2f(up[(size_t)j * DI]);
    zB[j] = zp[(size_t)j * 4096];
  }

#pragma unroll 1
  for (int g = 0; g < 8; ++g) {
    float dN[8] = {}, uN[8] = {}, zN[8] = {};
    if (g + 1 < 8) {
      const int nr = (g + 1) * 8;
#pragma unroll
      for (int j = 0; j < 8; ++j) {
        dN[j] = dp[(size_t)(nr + j) * DI];
        uN[j] = bf2f(up[(size_t)(nr + j) * DI]);
        zN[j] = zp[(size_t)(nr + j) * 4096];
      }
    }
#pragma unroll
    for (int j = 0; j < 8; ++j) {
      const float dlt = dB[j];
      const float u = uB[j];
      const float t = dlt * u;
      const float4 B0 = *(const float4*)&Bsh[g * 8 + j][half * 8];
      const float4 B1 = *(const float4*)&Bsh[g * 8 + j][half * 8 + 4];
      const float4 C0 = *(const float4*)&Csh[g * 8 + j][half * 8];
      const float4 C1 = *(const float4*)&Csh[g * 8 + j][half * 8 + 4];
      x[0] = fmaf(fexp2(dlt * Av2[0]), x[0], t * B0.x);
      x[1] = fmaf(fexp2(dlt * Av2[1]), x[1], t * B0.y);
      x[2] = fmaf(fexp2(dlt * Av2[2]), x[2], t * B0.z);
      x[3] = fmaf(fexp2(dlt * Av2[3]), x[3], t * B0.w);
      x[4] = fmaf(fexp2(dlt * Av2[4]), x[4], t * B1.x);
      x[5] = fmaf(fexp2(dlt * Av2[5]), x[5], t * B1.y);
      x[6] = fmaf(fexp2(dlt * Av2[6]), x[6], t * B1.z);
      x[7] = fmaf(fexp2(dlt * Av2[7]), x[7], t * B1.w);
      float y = x[0] * C0.x;
      y = fmaf(x[1], C0.y, y);
      y = fmaf(x[2], C0.z, y);
      y = fmaf(x[3], C0.w, y);
      y = fmaf(x[4], C1.x, y);
      y = fmaf(x[5], C1.y, y);
      y = fmaf(x[6], C1.z, y);
      y = fmaf(x[7], C1.w, y);
      y += __shfl_xor(y, 1);
      const float z = zB[j];
      const float sig = z / (1.f + __expf(-z));
      const float gv = fmaf(u, Dsk, y) * sig;
      if (!half) yb[(size_t)(row0 + g * 8 + j) * 8192 + d] = f2bf(gv);
    }
#pragma unroll
    for (int j = 0; j < 8; ++j) { dB[j] = dN[j]; uB[j] = uN[j]; zB[j] = zN[j]; }
  }
}

extern "C" void kernel_launch(void* const* d_in, const int* in_sizes, int n_in,
                              void* d_out, int out_size, void* d_ws, size_t ws_size,
                              hipStream_t stream) {
  const float* hidden  = (const float*)d_in[0];
  const float* Win     = (const float*)d_in[1];
  const float* Wx      = (const float*)d_in[2];
  const float* Wdt     = (const float*)d_in[3];
  const float* dt_bias = (const float*)d_in[4];
  const float* Wout    = (const float*)d_in[5];
  const float* dwk     = (const float*)d_in[6];
  const float* dwb     = (const float*)d_in[7];
  const float* A_log   = (const float*)d_in[8];
  const float* Dskip   = (const float*)d_in[9];

  // ws (64 MB): xz 32MB | shared16 (WinT -> xdbl partials -> delta) 16MB
  //             | [48,56M) xcb bf16 | [56,60M) WoutT bf16 | [60,64M) free
  // xz per-row float layout: [0,1024) y-bf16 | [1024,2048) scan stash | [2048,4096) z
  char* ws = (char*)d_ws;
  float* xz       = (float*)ws;
  float* shared16 = (float*)(ws + (32u << 20));
  ushortT* xcb    = (ushortT*)(ws + (48u << 20));
  ushortT* WoutT  = (ushortT*)(ws + (56u << 20));
  // d_out (8 MB) scratch: hidb [0,4M) (dead after GEMM1); xdbl128 [4M,5M);
  //                       WxT [5M,5.5M); WdtT [5.5M,5.75M); dtb [5.75M,6M)
  // all dead before gemm_out overwrites d_out with the final result.
  char* dob = (char*)d_out;
  ushortT* hidb = (ushortT*)dob;
  float* xdbl   = (float*)(dob + (4u << 20));
  ushortT* WxT  = (ushortT*)(dob + (5u << 20));
  ushortT* WdtT = (ushortT*)(dob + (5u << 20) + (512u << 10));
  ushortT* dtb  = (ushortT*)(dob + (5u << 20) + (768u << 10));

  // 1. fused prep: hidden->bf16, Win^T, Wx pad^T, Wdt^T, Wout^T
  prep_all<<<dim3(9344), 256, 0, stream>>>(hidden, hidb, Win, (ushortT*)shared16,
                                           Wx, WxT, Wdt, WdtT, Wout, WoutT);
  // 2. GEMM1: xz = hidden @ Win  (M=2048, N=4096, K=1024); 128x128, 8 waves, 512 blocks
  gemm1_big<<<dim3(4096 / 128, 2048 / 128), 512, 0, stream>>>(
      hidb, DM, (ushortT*)shared16, DM, xz, 2 * DI, DM);
  // 3. depthwise conv + silu -> xc bf16 (8-row tiles)
  conv_silu<<<dim3(B_SZ * L_SZ / 8, DI / 256), 256, 0, stream>>>(xz, dwk, dwb, xcb);
  // 4. x_dbl partials (K-split 8) -> shared16 [0,8M) (WinT dead), then reduce (+dt bf16)
  gemm_xdbl_mfma<<<dim3(B_SZ * L_SZ / 64, KSPLIT), 256, 0, stream>>>(
      xcb, WxT, shared16);
  xdbl_reduce<<<dim3(B_SZ * L_SZ * XDLD / 1024), 256, 0, stream>>>(shared16, xdbl, dtb);
  // 5. delta = softplus(dt @ Wdt + bias): pure-bf16 MFMA, single K=64 stage, 1024 blocks
  gemm_delta_mfma<<<dim3(B_SZ * L_SZ / 64, DI / 64), 256, 0, stream>>>(
      dtb, WdtT, dt_bias, shared16);
  // 6-7. chunked selective scan, 2-thr/d 8-state variant; phase3 folds the chunk combine
  scan_phase1<<<dim3(512), 256, 0, stream>>>(
      shared16, xcb, xdbl, A_log, xz);
  scan_phase3<<<dim3(512), 256, 0, stream>>>(
      shared16, xcb, xdbl, A_log, Dskip, xz);
  // 8. GEMM4: out = y @ Wout (M=2048, N=1024, K=2048), direct write to d_out
  gemm_out<<<dim3(DM / 64, 2048 / 64), 256, 0, stream>>>(
      (ushortT*)xz, 4 * DI, WoutT, DI, (float*)d_out);
}

// Round 9
// 212.747 us; speedup vs baseline: 1.6773x; 1.0559x over previous
//
#include <hip/hip_runtime.h>
#include <hip/hip_bf16.h>
#include <math.h>

#define B_SZ 2
#define L_SZ 1024
#define DM 1024
#define DI 2048
#define NS 16
#define DTR 64
#define NCHUNK 16
#define CLEN 64
#define XDLD 128  // padded x_dbl leading dim
#define KSPLIT 8

typedef unsigned short ushortT;
typedef __attribute__((ext_vector_type(8))) short short8;
typedef __attribute__((ext_vector_type(4))) float floatx4;

__device__ __forceinline__ ushortT f2bf(float f) {
  unsigned u = __float_as_uint(f);
  unsigned r = (u + 0x7fff + ((u >> 16) & 1)) >> 16;
  return (ushortT)r;
}

__device__ __forceinline__ float bf2f(ushortT v) {
  return __uint_as_float((unsigned)v << 16);
}

__device__ __forceinline__ float fexp2(float x) {
  float r;
  asm("v_exp_f32 %0, %1" : "=v"(r) : "v"(x));
  return r;
}

__device__ __forceinline__ void gl2lds16(const void* g, void* l) {
  __builtin_amdgcn_global_load_lds(
      (const __attribute__((address_space(1))) unsigned int*)g,
      (__attribute__((address_space(3))) unsigned int*)l, 16, 0, 0);
}

// Scan-state stash lives in the dead strided region of xz: floats [1024,2048)
// of each 4096-float row. i in [0, 2M): aprod at i, sfin at i + 1M.
__device__ __forceinline__ unsigned stash_addr(unsigned i) {
  return (i >> 10) * 4096 + 1024 + (i & 1023);
}

// ---------------- fused prep: cvt + 3 transposes + wx_pad ----------------
__device__ __forceinline__ void tr_body(const float* __restrict__ src,
                                        ushortT* __restrict__ dst, int R, int C,
                                        int bx, int by, int tx, int ty,
                                        float (*t)[33]) {
#pragma unroll
  for (int j = 0; j < 4; ++j)
    t[ty + j * 8][tx] = src[(size_t)(by + ty + j * 8) * C + bx + tx];
  __syncthreads();
#pragma unroll
  for (int j = 0; j < 4; ++j)
    dst[(size_t)(bx + ty + j * 8) * R + by + tx] = f2bf(t[tx][ty + j * 8]);
}

// grid ranges: [0,2048) cvt hidden | [2048,6144) Win-T | [6144,7168) Wx pad-T
//              [7168,7296) Wdt-T | [7296,9344) Wout-T
__global__ __launch_bounds__(256) void prep_all(
    const float* __restrict__ hidden, ushortT* __restrict__ hidb,
    const float* __restrict__ Win, ushortT* __restrict__ WinT,
    const float* __restrict__ Wx, ushortT* __restrict__ WxT,
    const float* __restrict__ Wdt, ushortT* __restrict__ WdtT,
    const float* __restrict__ Wout, ushortT* __restrict__ WoutT) {
  __shared__ float t[32][33];
  const int blk = blockIdx.x;
  const int tid = threadIdx.x;
  const int tx = tid & 31, ty = tid >> 5;
  if (blk < 2048) {
    const int i = blk * 256 + tid;
    float4 v = ((const float4*)hidden)[i];
    unsigned lo = (unsigned)f2bf(v.x) | ((unsigned)f2bf(v.y) << 16);
    unsigned hi = (unsigned)f2bf(v.z) | ((unsigned)f2bf(v.w) << 16);
    ((uint2*)hidb)[i] = make_uint2(lo, hi);
  } else if (blk < 6144) {
    const int rel = blk - 2048;  // (128, 32): C=4096, R=1024
    tr_body(Win, WinT, DM, 2 * DI, (rel & 127) * 32, (rel >> 7) * 32, tx, ty, t);
  } else if (blk < 7168) {
    const int rel = blk - 6144;  // (8, 128)
    const int k = (rel & 7) * 256 + tid;
    const int n = rel >> 3;
    WxT[(size_t)n * DI + k] = (n < 96) ? f2bf(Wx[(size_t)k * 96 + n]) : (ushortT)0;
  } else if (blk < 7296) {
    const int rel = blk - 7168;  // (64, 2): C=2048, R=64
    tr_body(Wdt, WdtT, DTR, DI, (rel & 63) * 32, (rel >> 6) * 32, tx, ty, t);
  } else {
    const int rel = blk - 7296;  // (32, 64): C=1024, R=2048
    tr_body(Wout, WoutT, DI, DM, (rel & 31) * 32, (rel >> 5) * 32, tx, ty, t);
  }
}

// ---------------- GEMM1: 128x128 tile, BK=64, 8 waves (512 thr), 512 blocks ----------------
__global__ __launch_bounds__(512) void gemm1_big(
    const ushortT* __restrict__ A, int lda,
    const ushortT* __restrict__ BT, int ldb,
    float* __restrict__ C, int ldc, int K) {
  __shared__ __align__(16) char smem[128 * 128 + 128 * 128];  // A 16KB | B 16KB
  char* As = smem;
  char* Bs = smem + 128 * 128;
  const int tid = threadIdx.x;
  const int lane = tid & 63;
  const int quad = lane >> 4;
  const int l16 = lane & 15;
  const int wid = tid >> 6;
  const int wm = wid & 1;   // 2 m-halves of 64
  const int wn = wid >> 1;  // 4 n-quarters of 32
  const int m0 = blockIdx.y * 128;
  const int n0 = blockIdx.x * 128;

  floatx4 acc[4][2] = {};

  for (int k0 = 0; k0 < K; k0 += 64) {
    for (int i = tid; i < 128 * 8; i += 512) {
      const int r = i >> 3, c = i & 7;
      const int cg = c ^ (r & 7);
      gl2lds16(A + (size_t)(m0 + r) * lda + k0 + cg * 8, As + (i - lane) * 16);
    }
    for (int i = tid; i < 128 * 8; i += 512) {
      const int r = i >> 3, c = i & 7;
      const int cg = c ^ (r & 7);
      gl2lds16(BT + (size_t)(n0 + r) * ldb + k0 + cg * 8, Bs + (i - lane) * 16);
    }
    __syncthreads();

    short8 afr[4][2], bfr[2][2];
#pragma unroll
    for (int i = 0; i < 4; ++i) {
      const int r = wm * 64 + i * 16 + l16;
#pragma unroll
      for (int s = 0; s < 2; ++s)
        afr[i][s] = *(const short8*)(As + r * 128 + (((s * 4 + quad) ^ (r & 7)) * 16));
    }
#pragma unroll
    for (int j = 0; j < 2; ++j) {
      const int r = wn * 32 + j * 16 + l16;
#pragma unroll
      for (int s = 0; s < 2; ++s)
        bfr[j][s] = *(const short8*)(Bs + r * 128 + (((s * 4 + quad) ^ (r & 7)) * 16));
    }
#pragma unroll
    for (int s = 0; s < 2; ++s)
#pragma unroll
      for (int i = 0; i < 4; ++i)
#pragma unroll
        for (int j = 0; j < 2; ++j)
          acc[i][j] = __builtin_amdgcn_mfma_f32_16x16x32_bf16(afr[i][s], bfr[j][s],
                                                              acc[i][j], 0, 0, 0);
    __syncthreads();
  }
#pragma unroll
  for (int i = 0; i < 4; ++i)
#pragma unroll
    for (int j = 0; j < 2; ++j)
#pragma unroll
      for (int r = 0; r < 4; ++r) {
        const int m = m0 + wm * 64 + i * 16 + quad * 4 + r;
        const int n = n0 + wn * 32 + j * 16 + l16;
        C[(size_t)m * ldc + n] = acc[i][j][r];
      }
}

// ---------------- GEMM4: 64x64 tile, BK=64, K=2048, 4 waves, 512 blocks, direct out --------
__global__ __launch_bounds__(256) void gemm_out(
    const ushortT* __restrict__ A, int lda,
    const ushortT* __restrict__ BT, int ldb,
    float* __restrict__ C) {
  __shared__ __align__(16) char smem[64 * 128 + 64 * 128];  // 8KB + 8KB
  char* As = smem;
  char* Bs = smem + 64 * 128;
  const int tid = threadIdx.x;
  const int lane = tid & 63;
  const int quad = lane >> 4;
  const int l16 = lane & 15;
  const int wid = tid >> 6;
  const int wm = wid & 1;   // 2 m-halves of 32
  const int wn = wid >> 1;  // 2 n-halves of 32
  const int m0 = blockIdx.y * 64;
  const int n0 = blockIdx.x * 64;

  floatx4 acc[2][2] = {};

  for (int k0 = 0; k0 < DI; k0 += 64) {
    for (int i = tid; i < 64 * 8; i += 256) {
      const int r = i >> 3, c = i & 7;
      const int cg = c ^ (r & 7);
      gl2lds16(A + (size_t)(m0 + r) * lda + k0 + cg * 8, As + (i - lane) * 16);
    }
    for (int i = tid; i < 64 * 8; i += 256) {
      const int r = i >> 3, c = i & 7;
      const int cg = c ^ (r & 7);
      gl2lds16(BT + (size_t)(n0 + r) * ldb + k0 + cg * 8, Bs + (i - lane) * 16);
    }
    __syncthreads();

    short8 afr[2][2], bfr[2][2];
#pragma unroll
    for (int i = 0; i < 2; ++i) {
      const int m = wm * 32 + i * 16 + l16;
#pragma unroll
      for (int s = 0; s < 2; ++s)
        afr[i][s] = *(const short8*)(As + m * 128 + (((s * 4 + quad) ^ (m & 7)) * 16));
    }
#pragma unroll
    for (int j = 0; j < 2; ++j) {
      const int n = wn * 32 + j * 16 + l16;
#pragma unroll
      for (int s = 0; s < 2; ++s)
        bfr[j][s] = *(const short8*)(Bs + n * 128 + (((s * 4 + quad) ^ (n & 7)) * 16));
    }
#pragma unroll
    for (int s = 0; s < 2; ++s)
#pragma unroll
      for (int i = 0; i < 2; ++i)
#pragma unroll
        for (int j = 0; j < 2; ++j)
          acc[i][j] = __builtin_amdgcn_mfma_f32_16x16x32_bf16(afr[i][s], bfr[j][s],
                                                              acc[i][j], 0, 0, 0);
    __syncthreads();
  }
#pragma unroll
  for (int i = 0; i < 2; ++i)
#pragma unroll
    for (int j = 0; j < 2; ++j)
#pragma unroll
      for (int r = 0; r < 4; ++r) {
        const int m = m0 + wm * 32 + i * 16 + quad * 4 + r;
        const int n = n0 + wn * 32 + j * 16 + l16;
        C[(size_t)m * DM + n] = acc[i][j][r];
      }
}

// ------------- x_dbl partials: xc(bf16) @ Wx (padded N=128), K-split via MFMA -------------
__global__ __launch_bounds__(256) void gemm_xdbl_mfma(
    const ushortT* __restrict__ xcb, const ushortT* __restrict__ WxT,
    float* __restrict__ part) {
  __shared__ __align__(16) char smem[64 * 64 + 128 * 64];
  char* As = smem;             // [64 r][64 B bf16]
  char* Bs = smem + 64 * 64;   // [128 r][64 B bf16]
  const int tid = threadIdx.x;
  const int lane = tid & 63;
  const int quad = lane >> 4;
  const int l16 = lane & 15;
  const int wid = tid >> 6;
  const int wm = wid & 1;
  const int wn = wid >> 1;
  const int m0 = blockIdx.x * 64;
  const int kbase = blockIdx.y * (DI / KSPLIT);

  floatx4 acc[2][4] = {};

  for (int kk = 0; kk < DI / KSPLIT; kk += 32) {
    const int k0 = kbase + kk;
    for (int i = tid; i < 64 * 4; i += 256) {
      const int r = i >> 2, c = i & 3;
      const int cg = c ^ (r & 3);
      gl2lds16(xcb + (size_t)(m0 + r) * DI + k0 + cg * 8, As + (i - lane) * 16);
    }
    for (int i = tid; i < 128 * 4; i += 256) {
      const int r = i >> 2, c = i & 3;
      const int cg = c ^ (r & 3);
      gl2lds16(WxT + (size_t)r * DI + k0 + cg * 8, Bs + (i - lane) * 16);
    }
    __syncthreads();

    short8 afr[2], bfr[4];
#pragma unroll
    for (int i = 0; i < 2; ++i) {
      const int m = wm * 32 + i * 16 + l16;
      afr[i] = *(const short8*)(As + m * 64 + ((quad ^ (m & 3)) * 16));
    }
#pragma unroll
    for (int j = 0; j < 4; ++j) {
      const int n = wn * 64 + j * 16 + l16;
      bfr[j] = *(const short8*)(Bs + n * 64 + ((quad ^ (n & 3)) * 16));
    }
#pragma unroll
    for (int i = 0; i < 2; ++i)
#pragma unroll
      for (int j = 0; j < 4; ++j)
        acc[i][j] = __builtin_amdgcn_mfma_f32_16x16x32_bf16(afr[i], bfr[j],
                                                            acc[i][j], 0, 0, 0);
    __syncthreads();
  }
  float* out = part + (size_t)blockIdx.y * (B_SZ * L_SZ * XDLD);
#pragma unroll
  for (int i = 0; i < 2; ++i)
#pragma unroll
    for (int j = 0; j < 4; ++j)
#pragma unroll
      for (int r = 0; r < 4; ++r) {
        const int m = m0 + wm * 32 + i * 16 + quad * 4 + r;
        const int n = wn * 64 + j * 16 + l16;
        out[(size_t)m * XDLD + n] = acc[i][j][r];
      }
}

// ------------- xdbl = sum of KSPLIT partials; also emit dt cols 0..63 as bf16 -------------
__global__ __launch_bounds__(256) void xdbl_reduce(const float* __restrict__ part,
                                                   float* __restrict__ xdbl,
                                                   ushortT* __restrict__ dtb) {
  const int i = blockIdx.x * 256 + threadIdx.x;  // float4 index, [0, 65536)
  float4 a = ((const float4*)part)[i];
#pragma unroll
  for (int s = 1; s < KSPLIT; ++s) {
    const float4 b = ((const float4*)part)[(size_t)s * (B_SZ * L_SZ * XDLD / 4) + i];
    a.x += b.x; a.y += b.y; a.z += b.z; a.w += b.w;
  }
  ((float4*)xdbl)[i] = a;
  // dt = xdbl[:, 0:64] -> compact bf16 [2048][64] for gemm_delta's A operand
  const int row = i >> 5;           // 32 float4 per 128-col row
  const int c4 = (i & 31) * 4;      // column of this float4
  if (c4 < DTR) {
    const unsigned lo = (unsigned)f2bf(a.x) | ((unsigned)f2bf(a.y) << 16);
    const unsigned hi = (unsigned)f2bf(a.z) | ((unsigned)f2bf(a.w) << 16);
    ((uint2*)dtb)[row * (DTR / 4) + (c4 >> 2)] = make_uint2(lo, hi);
  }
}

// ------------- causal depthwise conv (k=4) + silu -> xcb (row-major) + xcu (tiled) --------
__global__ __launch_bounds__(256) void conv_silu(
    const float* __restrict__ xz, const float* __restrict__ kern,
    const float* __restrict__ bias, ushortT* __restrict__ xcb,
    ushortT* __restrict__ xcu) {
  const int d = blockIdx.y * 256 + threadIdx.x;
  const int b = blockIdx.x >> 7;           // 128 8-row chunks per batch
  const int l0 = (blockIdx.x & 127) * 8;
  const int row0 = b * L_SZ + l0;
  const float k0v = kern[0 * DI + d], k1v = kern[1 * DI + d];
  const float k2v = kern[2 * DI + d], k3v = kern[3 * DI + d];
  float xv[11];
#pragma unroll
  for (int i = 0; i < 11; ++i) {
    const int l = l0 - 3 + i;
    xv[i] = (l >= 0) ? xz[((size_t)(b * L_SZ + l)) * 4096 + d] : 0.f;
  }
  const float bs = bias[d];
  short8 sv;
#pragma unroll
  for (int j = 0; j < 8; ++j) {
    float a = bs;
    a = fmaf(xv[j], k0v, a);
    a = fmaf(xv[j + 1], k1v, a);
    a = fmaf(xv[j + 2], k2v, a);
    a = fmaf(xv[j + 3], k3v, a);
    const ushortT h = f2bf(a / (1.f + __expf(-a)));
    xcb[(size_t)(row0 + j) * DI + d] = h;
    sv[j] = (short)h;
  }
  *(short8*)(xcu + ((size_t)(row0 >> 3) * DI + d) * 8) = sv;
}

// ------------- delta = softplus(dt @ Wdt + dt_bias) -> TILED [(l>>3)][d][l&7] f32 ---------
__global__ __launch_bounds__(256) void gemm_delta_mfma(
    const ushortT* __restrict__ dtb, const ushortT* __restrict__ WdtT,
    const float* __restrict__ dt_bias, float* __restrict__ delta) {
  __shared__ __align__(16) char smem[64 * 128 + 64 * 128];  // A 8KB | B 8KB
  char* As = smem;
  char* Bs = smem + 64 * 128;
  const int tid = threadIdx.x;
  const int lane = tid & 63;
  const int quad = lane >> 4;
  const int l16 = lane & 15;
  const int wid = tid >> 6;
  const int wm = wid & 1;
  const int wn = wid >> 1;
  const int m0 = blockIdx.x * 64;
  const int n0 = blockIdx.y * 64;

  for (int i = tid; i < 64 * 8; i += 256) {
    const int r = i >> 3, c = i & 7;
    const int cg = c ^ (r & 7);
    gl2lds16(dtb + (size_t)(m0 + r) * DTR + cg * 8, As + (i - lane) * 16);
  }
  for (int i = tid; i < 64 * 8; i += 256) {
    const int r = i >> 3, c = i & 7;
    const int cg = c ^ (r & 7);
    gl2lds16(WdtT + (size_t)(n0 + r) * DTR + cg * 8, Bs + (i - lane) * 16);
  }
  __syncthreads();

  floatx4 acc[2][2] = {};
  short8 afr[2][2], bfr[2][2];
#pragma unroll
  for (int i = 0; i < 2; ++i) {
    const int m = wm * 32 + i * 16 + l16;
#pragma unroll
    for (int s = 0; s < 2; ++s)
      afr[i][s] = *(const short8*)(As + m * 128 + (((s * 4 + quad) ^ (m & 7)) * 16));
  }
#pragma unroll
  for (int j = 0; j < 2; ++j) {
    const int n = wn * 32 + j * 16 + l16;
#pragma unroll
    for (int s = 0; s < 2; ++s)
      bfr[j][s] = *(const short8*)(Bs + n * 128 + (((s * 4 + quad) ^ (n & 7)) * 16));
  }
#pragma unroll
  for (int s = 0; s < 2; ++s)
#pragma unroll
    for (int i = 0; i < 2; ++i)
#pragma unroll
      for (int j = 0; j < 2; ++j)
        acc[i][j] = __builtin_amdgcn_mfma_f32_16x16x32_bf16(afr[i][s], bfr[j][s],
                                                            acc[i][j], 0, 0, 0);

#pragma unroll
  for (int i = 0; i < 2; ++i)
#pragma unroll
    for (int j = 0; j < 2; ++j) {
      const int n = n0 + wn * 32 + j * 16 + l16;
      const float bias = dt_bias[n];
#pragma unroll
      for (int r = 0; r < 4; ++r) {
        const int m = m0 + wm * 32 + i * 16 + quad * 4 + r;
        const float a = acc[i][j][r] + bias;
        // softplus: a>20 guard covers overflow; expf underflow -> log(1)=0 is exact.
        const float sp = (a > 20.f) ? a : __logf(1.f + __expf(a));
        delta[(((size_t)(m >> 3)) * DI + n) * 8 + (m & 7)] = sp;
      }
    }
}

// ------------- scan phase 1: per-chunk transition (tiled delta/u reads) -------------
// 512 blocks x 256 thr: block = (b, chunk c, 128 d's); 2 thr/d, 8 states each.
// Per 8-step group: 2 float4 (delta) + 1 short8 (u) coalesced loads, one group ahead.
__global__ __launch_bounds__(256) void scan_phase1(
    const float* __restrict__ dt_t, const ushortT* __restrict__ xcu,
    const float* __restrict__ xdbl, const float* __restrict__ A_log,
    float* __restrict__ xz) {
  const int bx = blockIdx.x;
  const int b = bx >> 8;
  const int c = (bx >> 4) & 15;
  const int dblk = bx & 15;
  const int tid = threadIdx.x;
  const int half = tid & 1;           // which 8 of the 16 states
  const int d = dblk * 128 + (tid >> 1);
  const int row0 = b * L_SZ + c * CLEN;
  const int r80 = row0 >> 3;

  __shared__ float Bsh[CLEN][16];
  for (int i = tid; i < CLEN * 16; i += 256)
    Bsh[i >> 4][i & 15] = xdbl[(size_t)(row0 + (i >> 4)) * XDLD + 64 + (i & 15)];

  // A with log2(e) folded: dA = exp2(delta * Av2)
  float Av2[8];
  {
    const float4 a0 = *(const float4*)&A_log[d * 16 + half * 8];
    const float4 a1 = *(const float4*)&A_log[d * 16 + half * 8 + 4];
    Av2[0] = -__expf(a0.x) * 1.44269504f;
    Av2[1] = -__expf(a0.y) * 1.44269504f;
    Av2[2] = -__expf(a0.z) * 1.44269504f;
    Av2[3] = -__expf(a0.w) * 1.44269504f;
    Av2[4] = -__expf(a1.x) * 1.44269504f;
    Av2[5] = -__expf(a1.y) * 1.44269504f;
    Av2[6] = -__expf(a1.z) * 1.44269504f;
    Av2[7] = -__expf(a1.w) * 1.44269504f;
  }

  const float* dp = dt_t + ((size_t)r80 * DI + d) * 8;
  const ushortT* up = xcu + ((size_t)r80 * DI + d) * 8;

  float4 dv0 = ((const float4*)dp)[0];
  float4 dv1 = ((const float4*)dp)[1];
  short8 uv = *(const short8*)up;
  float x[8] = {};
  float sd = 0.f;
  __syncthreads();

#pragma unroll 1
  for (int g = 0; g < 8; ++g) {
    float4 nd0 = make_float4(0.f, 0.f, 0.f, 0.f), nd1 = nd0;
    short8 nuv = {};
    if (g + 1 < 8) {
      const float* p = dp + (size_t)(g + 1) * DI * 8;
      nd0 = ((const float4*)p)[0];
      nd1 = ((const float4*)p)[1];
      nuv = *(const short8*)(up + (size_t)(g + 1) * DI * 8);
    }
    const float dB[8] = {dv0.x, dv0.y, dv0.z, dv0.w, dv1.x, dv1.y, dv1.z, dv1.w};
#pragma unroll
    for (int j = 0; j < 8; ++j) {
      const float dlt = dB[j];
      const float t = dlt * bf2f((ushortT)uv[j]);
      const float4 B0 = *(const float4*)&Bsh[g * 8 + j][half * 8];
      const float4 B1 = *(const float4*)&Bsh[g * 8 + j][half * 8 + 4];
      sd += dlt;
      x[0] = fmaf(fexp2(dlt * Av2[0]), x[0], t * B0.x);
      x[1] = fmaf(fexp2(dlt * Av2[1]), x[1], t * B0.y);
      x[2] = fmaf(fexp2(dlt * Av2[2]), x[2], t * B0.z);
      x[3] = fmaf(fexp2(dlt * Av2[3]), x[3], t * B0.w);
      x[4] = fmaf(fexp2(dlt * Av2[4]), x[4], t * B1.x);
      x[5] = fmaf(fexp2(dlt * Av2[5]), x[5], t * B1.y);
      x[6] = fmaf(fexp2(dlt * Av2[6]), x[6], t * B1.z);
      x[7] = fmaf(fexp2(dlt * Av2[7]), x[7], t * B1.w);
    }
    dv0 = nd0; dv1 = nd1; uv = nuv;
  }
  const unsigned e = ((unsigned)((b * NCHUNK + c) * DI + d)) * 16 + half * 8;
  *(float4*)&xz[stash_addr(e)] =
      make_float4(fexp2(Av2[0] * sd), fexp2(Av2[1] * sd),
                  fexp2(Av2[2] * sd), fexp2(Av2[3] * sd));
  *(float4*)&xz[stash_addr(e + 4)] =
      make_float4(fexp2(Av2[4] * sd), fexp2(Av2[5] * sd),
                  fexp2(Av2[6] * sd), fexp2(Av2[7] * sd));
  *(float4*)&xz[stash_addr((1u << 20) + e)] = make_float4(x[0], x[1], x[2], x[3]);
  *(float4*)&xz[stash_addr((1u << 20) + e + 4)] = make_float4(x[4], x[5], x[6], x[7]);
}

// ------------- scan phase 3: chunk-init combine + rescan + y + skip + gate -> bf16 y -------
// Tiled delta/u reads; z read strided with on-the-fly silu (as round-6).
__global__ __launch_bounds__(256) void scan_phase3(
    const float* __restrict__ dt_t, const ushortT* __restrict__ xcu,
    const float* __restrict__ xdbl, const float* __restrict__ A_log,
    const float* __restrict__ Dskip, float* __restrict__ xz) {
  const int bx = blockIdx.x;
  const int b = bx >> 8;
  const int c = (bx >> 4) & 15;
  const int dblk = bx & 15;
  const int tid = threadIdx.x;
  const int half = tid & 1;
  const int d = dblk * 128 + (tid >> 1);
  const int row0 = b * L_SZ + c * CLEN;
  const int r80 = row0 >> 3;

  __shared__ float Bsh[CLEN][16], Csh[CLEN][16];
  for (int i = tid; i < CLEN * 32; i += 256) {
    const int r = i >> 5, q = i & 31;
    const float v = xdbl[(size_t)(row0 + r) * XDLD + 64 + q];
    if (q < 16) Bsh[r][q] = v; else Csh[r][q - 16] = v;
  }

  float Av2[8];
  {
    const float4 a0 = *(const float4*)&A_log[d * 16 + half * 8];
    const float4 a1 = *(const float4*)&A_log[d * 16 + half * 8 + 4];
    Av2[0] = -__expf(a0.x) * 1.44269504f;
    Av2[1] = -__expf(a0.y) * 1.44269504f;
    Av2[2] = -__expf(a0.z) * 1.44269504f;
    Av2[3] = -__expf(a0.w) * 1.44269504f;
    Av2[4] = -__expf(a1.x) * 1.44269504f;
    Av2[5] = -__expf(a1.y) * 1.44269504f;
    Av2[6] = -__expf(a1.z) * 1.44269504f;
    Av2[7] = -__expf(a1.w) * 1.44269504f;
  }
  const float Dsk = Dskip[d];

  // chunk-init: combine P/S of chunks < c — ascending cc, same fma order as before.
  float x[8] = {};
  for (int cc = 0; cc < c; ++cc) {
    const unsigned e = ((unsigned)((b * NCHUNK + cc) * DI + d)) * 16 + half * 8;
    const float4 P0 = *(const float4*)&xz[stash_addr(e)];
    const float4 P1 = *(const float4*)&xz[stash_addr(e + 4)];
    const float4 S0 = *(const float4*)&xz[stash_addr((1u << 20) + e)];
    const float4 S1 = *(const float4*)&xz[stash_addr((1u << 20) + e + 4)];
    x[0] = fmaf(P0.x, x[0], S0.x);
    x[1] = fmaf(P0.y, x[1], S0.y);
    x[2] = fmaf(P0.z, x[2], S0.z);
    x[3] = fmaf(P0.w, x[3], S0.w);
    x[4] = fmaf(P1.x, x[4], S1.x);
    x[5] = fmaf(P1.y, x[5], S1.y);
    x[6] = fmaf(P1.z, x[6], S1.z);
    x[7] = fmaf(P1.w, x[7], S1.w);
  }
  __syncthreads();

  const float* dp = dt_t + ((size_t)r80 * DI + d) * 8;
  const ushortT* up = xcu + ((size_t)r80 * DI + d) * 8;
  const float* zp = xz + (size_t)row0 * 4096 + DI + d;
  ushortT* yb = (ushortT*)xz;

  float4 dv0 = ((const float4*)dp)[0];
  float4 dv1 = ((const float4*)dp)[1];
  short8 uv = *(const short8*)up;
  float zB[8];
#pragma unroll
  for (int j = 0; j < 8; ++j) zB[j] = zp[(size_t)j * 4096];

#pragma unroll 1
  for (int g = 0; g < 8; ++g) {
    float4 nd0 = make_float4(0.f, 0.f, 0.f, 0.f), nd1 = nd0;
    short8 nuv = {};
    float zN[8] = {};
    if (g + 1 < 8) {
      const float* p = dp + (size_t)(g + 1) * DI * 8;
      nd0 = ((const float4*)p)[0];
      nd1 = ((const float4*)p)[1];
      nuv = *(const short8*)(up + (size_t)(g + 1) * DI * 8);
      const int nr = (g + 1) * 8;
#pragma unroll
      for (int j = 0; j < 8; ++j) zN[j] = zp[(size_t)(nr + j) * 4096];
    }
    const float dB[8] = {dv0.x, dv0.y, dv0.z, dv0.w, dv1.x, dv1.y, dv1.z, dv1.w};
#pragma unroll
    for (int j = 0; j < 8; ++j) {
      const float dlt = dB[j];
      const float u = bf2f((ushortT)uv[j]);
      const float t = dlt * u;
      const float4 B0 = *(const float4*)&Bsh[g * 8 + j][half * 8];
      const float4 B1 = *(const float4*)&Bsh[g * 8 + j][half * 8 + 4];
      const float4 C0 = *(const float4*)&Csh[g * 8 + j][half * 8];
      const float4 C1 = *(const float4*)&Csh[g * 8 + j][half * 8 + 4];
      x[0] = fmaf(fexp2(dlt * Av2[0]), x[0], t * B0.x);
      x[1] = fmaf(fexp2(dlt * Av2[1]), x[1], t * B0.y);
      x[2] = fmaf(fexp2(dlt * Av2[2]), x[2], t * B0.z);
      x[3] = fmaf(fexp2(dlt * Av2[3]), x[3], t * B0.w);
      x[4] = fmaf(fexp2(dlt * Av2[4]), x[4], t * B1.x);
      x[5] = fmaf(fexp2(dlt * Av2[5]), x[5], t * B1.y);
      x[6] = fmaf(fexp2(dlt * Av2[6]), x[6], t * B1.z);
      x[7] = fmaf(fexp2(dlt * Av2[7]), x[7], t * B1.w);
      float y = x[0] * C0.x;
      y = fmaf(x[1], C0.y, y);
      y = fmaf(x[2], C0.z, y);
      y = fmaf(x[3], C0.w, y);
      y = fmaf(x[4], C1.x, y);
      y = fmaf(x[5], C1.y, y);
      y = fmaf(x[6], C1.z, y);
      y = fmaf(x[7], C1.w, y);
      y += __shfl_xor(y, 1);
      const float z = zB[j];
      const float sig = z / (1.f + __expf(-z));
      const float gv = fmaf(u, Dsk, y) * sig;
      if (!half) yb[(size_t)(row0 + g * 8 + j) * 8192 + d] = f2bf(gv);
    }
    dv0 = nd0; dv1 = nd1; uv = nuv;
#pragma unroll
    for (int j = 0; j < 8; ++j) zB[j] = zN[j];
  }
}

extern "C" void kernel_launch(void* const* d_in, const int* in_sizes, int n_in,
                              void* d_out, int out_size, void* d_ws, size_t ws_size,
                              hipStream_t stream) {
  const float* hidden  = (const float*)d_in[0];
  const float* Win     = (const float*)d_in[1];
  const float* Wx      = (const float*)d_in[2];
  const float* Wdt     = (const float*)d_in[3];
  const float* dt_bias = (const float*)d_in[4];
  const float* Wout    = (const float*)d_in[5];
  const float* dwk     = (const float*)d_in[6];
  const float* dwb     = (const float*)d_in[7];
  const float* A_log   = (const float*)d_in[8];
  const float* Dskip   = (const float*)d_in[9];

  // ws (64 MB): xz 32MB | shared16 (WinT -> xdbl partials -> delta_t) 16MB
  //             | [48,56M) xcb row-major bf16 | [56,60M) WoutT bf16 | [60,64M) xcu tiled
  // xz per-row float layout: [0,1024) y-bf16 | [1024,2048) scan stash | [2048,4096) z
  char* ws = (char*)d_ws;
  float* xz       = (float*)ws;
  float* shared16 = (float*)(ws + (32u << 20));
  ushortT* xcb    = (ushortT*)(ws + (48u << 20));
  ushortT* WoutT  = (ushortT*)(ws + (56u << 20));
  ushortT* xcu    = (ushortT*)(ws + (60u << 20));
  // d_out (8 MB) scratch: hidb [0,4M) (dead after GEMM1); xdbl128 [4M,5M);
  //                       WxT [5M,5.5M); WdtT [5.5M,5.75M); dtb [5.75M,6M)
  char* dob = (char*)d_out;
  ushortT* hidb = (ushortT*)dob;
  float* xdbl   = (float*)(dob + (4u << 20));
  ushortT* WxT  = (ushortT*)(dob + (5u << 20));
  ushortT* WdtT = (ushortT*)(dob + (5u << 20) + (512u << 10));
  ushortT* dtb  = (ushortT*)(dob + (5u << 20) + (768u << 10));

  // 1. fused prep: hidden->bf16, Win^T, Wx pad^T, Wdt^T, Wout^T
  prep_all<<<dim3(9344), 256, 0, stream>>>(hidden, hidb, Win, (ushortT*)shared16,
                                           Wx, WxT, Wdt, WdtT, Wout, WoutT);
  // 2. GEMM1: xz = hidden @ Win  (M=2048, N=4096, K=1024); 128x128, 8 waves, 512 blocks
  gemm1_big<<<dim3(4096 / 128, 2048 / 128), 512, 0, stream>>>(
      hidb, DM, (ushortT*)shared16, DM, xz, 2 * DI, DM);
  // 3. conv+silu -> xcb (row-major) + xcu (tiled)
  conv_silu<<<dim3(B_SZ * L_SZ / 8, DI / 256), 256, 0, stream>>>(
      xz, dwk, dwb, xcb, xcu);
  // 4. x_dbl partials (K-split 8) -> shared16 [0,8M) (WinT dead), then reduce (+dt bf16)
  gemm_xdbl_mfma<<<dim3(B_SZ * L_SZ / 64, KSPLIT), 256, 0, stream>>>(
      xcb, WxT, shared16);
  xdbl_reduce<<<dim3(B_SZ * L_SZ * XDLD / 1024), 256, 0, stream>>>(shared16, xdbl, dtb);
  // 5. delta = softplus(dt @ Wdt + bias) -> TILED f32 in shared16
  gemm_delta_mfma<<<dim3(B_SZ * L_SZ / 64, DI / 64), 256, 0, stream>>>(
      dtb, WdtT, dt_bias, shared16);
  // 6-7. chunked selective scan with tiled delta/u layouts
  scan_phase1<<<dim3(512), 256, 0, stream>>>(
      shared16, xcu, xdbl, A_log, xz);
  scan_phase3<<<dim3(512), 256, 0, stream>>>(
      shared16, xcu, xdbl, A_log, Dskip, xz);
  // 8. GEMM4: out = y @ Wout (M=2048, N=1024, K=2048), direct write to d_out
  gemm_out<<<dim3(DM / 64, 2048 / 64), 256, 0, stream>>>(
      (ushortT*)xz, 4 * DI, WoutT, DI, (float*)d_out);
}